// Round 1
// baseline (1240.649 us; speedup 1.0000x reference)
//
#include <hip/hip_runtime.h>

#define N_NODES 100000
#define N_EDGES 1200000

// ---- degree via atomics (dst includes every edge; +1 self-loop added in dinv) ----
__global__ void deg_kernel(const int* __restrict__ dst, float* __restrict__ deg, int E) {
    int e = blockIdx.x * blockDim.x + threadIdx.x;
    if (e < E) atomicAdd(&deg[dst[e]], 1.0f);
}

__global__ void dinv_kernel(float* __restrict__ degdinv, int N) {
    int i = blockIdx.x * blockDim.x + threadIdx.x;
    if (i < N) degdinv[i] = rsqrtf(degdinv[i] + 1.0f);  // +1 = self loop; always > 0
}

// ---- out[i,:] = dinv[i] * (X[i,:] @ W)   (K x 64 weight staged in LDS) ----
template <int K>
__global__ __launch_bounds__(256) void gemm_scale(const float* __restrict__ X,
                                                  const float* __restrict__ W,
                                                  const float* __restrict__ dinv,
                                                  float* __restrict__ out, int N) {
    __shared__ float wl[K * 64];
    for (int idx = threadIdx.x; idx < K * 64; idx += 256) wl[idx] = W[idx];
    __syncthreads();
    int i = blockIdx.x * 256 + threadIdx.x;
    if (i >= N) return;
    const float4* xr = reinterpret_cast<const float4*>(X + (size_t)i * K);
    float4 acc[16];
#pragma unroll
    for (int j = 0; j < 16; j++) acc[j] = make_float4(0.f, 0.f, 0.f, 0.f);
#pragma unroll 2
    for (int k4 = 0; k4 < K / 4; k4++) {
        float4 xv = xr[k4];
        const float* w0 = wl + k4 * 4 * 64;
#pragma unroll
        for (int j = 0; j < 16; j++) {
            float4 wa = reinterpret_cast<const float4*>(w0)[j];
            float4 wb = reinterpret_cast<const float4*>(w0 + 64)[j];
            float4 wc = reinterpret_cast<const float4*>(w0 + 128)[j];
            float4 wd = reinterpret_cast<const float4*>(w0 + 192)[j];
            acc[j].x += xv.x * wa.x + xv.y * wb.x + xv.z * wc.x + xv.w * wd.x;
            acc[j].y += xv.x * wa.y + xv.y * wb.y + xv.z * wc.y + xv.w * wd.y;
            acc[j].z += xv.x * wa.z + xv.y * wb.z + xv.z * wc.z + xv.w * wd.z;
            acc[j].w += xv.x * wa.w + xv.y * wb.w + xv.z * wc.w + xv.w * wd.w;
        }
    }
    float di = dinv[i];
    float4* op = reinterpret_cast<float4*>(out + (size_t)i * 64);
#pragma unroll
    for (int j = 0; j < 16; j++) {
        float4 v = acc[j];
        v.x *= di; v.y *= di; v.z *= di; v.w *= di;
        op[j] = v;
    }
}

// ---- agg[dst,:] += t[src,:]  (wave per edge, lane = feature) ----
__global__ __launch_bounds__(256) void scatter_kernel(const int* __restrict__ src,
                                                      const int* __restrict__ dst,
                                                      const float* __restrict__ t,
                                                      float* __restrict__ agg, int E) {
    int lane = threadIdx.x & 63;
    int wid = blockIdx.x * 4 + (threadIdx.x >> 6);
    int nw = gridDim.x * 4;
    for (int e = wid; e < E; e += nw) {
        int s = src[e], d = dst[e];
        float v = t[(size_t)s * 64 + lane];
        atomicAdd(&agg[(size_t)d * 64 + lane], v);
    }
}

// ---- h = relu(dinv[i]*agg + b) ----
__global__ void relu_bias_kernel(const float* __restrict__ agg, const float* __restrict__ dinv,
                                 const float* __restrict__ b, float* __restrict__ out, int N64) {
    int t = blockIdx.x * blockDim.x + threadIdx.x;
    if (t >= N64) return;
    int i = t >> 6, f = t & 63;
    float v = dinv[i] * agg[t] + b[f];
    out[t] = fmaxf(v, 0.0f);
}

// ---- per-node: h2 = dinv*agg + b2; s = h2 . Wl; atomic into per-graph sum/count ----
__global__ __launch_bounds__(256) void final_kernel(const float* __restrict__ agg,
                                                    const float* __restrict__ dinv,
                                                    const float* __restrict__ b2,
                                                    const float* __restrict__ Wl,
                                                    const int* __restrict__ batch,
                                                    float* __restrict__ gsum,
                                                    float* __restrict__ gcnt, int N) {
    int lane = threadIdx.x & 63;
    int i = blockIdx.x * 4 + (threadIdx.x >> 6);
    if (i >= N) return;
    float h = dinv[i] * agg[(size_t)i * 64 + lane] + b2[lane];
    float p = h * Wl[lane];
#pragma unroll
    for (int off = 32; off; off >>= 1) p += __shfl_down(p, off, 64);
    if (lane == 0) {
        int g = batch[i];
        atomicAdd(&gsum[g], p);
        atomicAdd(&gcnt[g], 1.0f);
    }
}

__global__ void out_kernel(const float* __restrict__ gsum, const float* __restrict__ gcnt,
                           const float* __restrict__ bl, float* __restrict__ out) {
    int g = threadIdx.x;
    out[g] = gsum[g] / fmaxf(gcnt[g], 1.0f) + bl[0];
}

extern "C" void kernel_launch(void* const* d_in, const int* in_sizes, int n_in,
                              void* d_out, int out_size, void* d_ws, size_t ws_size,
                              hipStream_t stream) {
    const float* x  = (const float*)d_in[0];
    const int*   ei = (const int*)d_in[1];
    const int*   batch = (const int*)d_in[2];
    const float* W1 = (const float*)d_in[3];
    const float* b1 = (const float*)d_in[4];
    const float* W2 = (const float*)d_in[5];
    const float* b2 = (const float*)d_in[6];
    const float* Wl = (const float*)d_in[7];
    const float* bl = (const float*)d_in[8];
    float* out = (float*)d_out;

    const int N = N_NODES, E = N_EDGES;
    const int* src = ei;
    const int* dst = ei + E;

    float* wsf  = (float*)d_ws;
    float* dinv = wsf;                         // N floats (used as deg first)
    float* buf1 = wsf + 100096;                // N*64, 16B-aligned
    float* buf2 = buf1 + 6400000;              // N*64
    float* gsum = buf2 + 6400000;              // 256
    float* gcnt = gsum + 256;                  // 256

    hipMemsetAsync(dinv, 0, N * sizeof(float), stream);
    hipMemsetAsync(gsum, 0, 512 * sizeof(float), stream);

    deg_kernel<<<(E + 255) / 256, 256, 0, stream>>>(dst, dinv, E);
    dinv_kernel<<<(N + 255) / 256, 256, 0, stream>>>(dinv, N);

    // Layer 1: t' = dinv*(x@W1); agg = t' (self loops); agg[dst]+=t'[src]; h1=relu(dinv*agg+b1)
    gemm_scale<128><<<(N + 255) / 256, 256, 0, stream>>>(x, W1, dinv, buf1, N);
    hipMemcpyAsync(buf2, buf1, (size_t)N * 64 * sizeof(float), hipMemcpyDeviceToDevice, stream);
    scatter_kernel<<<4096, 256, 0, stream>>>(src, dst, buf1, buf2, E);
    relu_bias_kernel<<<(N * 64 + 255) / 256, 256, 0, stream>>>(buf2, dinv, b1, buf1, N * 64);

    // Layer 2: t2' = dinv*(h1@W2); agg2 = t2'; agg2[dst]+=t2'[src]; fused epilogue+pool
    gemm_scale<64><<<(N + 255) / 256, 256, 0, stream>>>(buf1, W2, dinv, buf2, N);
    hipMemcpyAsync(buf1, buf2, (size_t)N * 64 * sizeof(float), hipMemcpyDeviceToDevice, stream);
    scatter_kernel<<<4096, 256, 0, stream>>>(src, dst, buf2, buf1, E);

    final_kernel<<<(N + 3) / 4, 256, 0, stream>>>(buf1, dinv, b2, Wl, batch, gsum, gcnt, N);
    out_kernel<<<1, 256, 0, stream>>>(gsum, gcnt, bl, out);
}

// Round 2
// 829.315 us; speedup vs baseline: 1.4960x; 1.4960x over previous
//
#include <hip/hip_runtime.h>

#define N_NODES 100000
#define N_EDGES 1200000

// ---- degree via atomics (dst includes every edge; +1 self-loop added in dinv) ----
__global__ void deg_kernel(const int* __restrict__ dst, float* __restrict__ deg, int E) {
    int e = blockIdx.x * blockDim.x + threadIdx.x;
    if (e < E) atomicAdd(&deg[dst[e]], 1.0f);
}

__global__ void dinv_kernel(float* __restrict__ degdinv, int N) {
    int i = blockIdx.x * blockDim.x + threadIdx.x;
    if (i < N) degdinv[i] = rsqrtf(degdinv[i] + 1.0f);  // +1 = self loop; always > 0
}

// ---- out[i,:] = dinv[i] * (X[i,:] @ W)   (K x 64 weight staged in LDS) ----
template <int K>
__global__ __launch_bounds__(256) void gemm_scale(const float* __restrict__ X,
                                                  const float* __restrict__ W,
                                                  const float* __restrict__ dinv,
                                                  float* __restrict__ out, int N) {
    __shared__ float wl[K * 64];
    for (int idx = threadIdx.x; idx < K * 64; idx += 256) wl[idx] = W[idx];
    __syncthreads();
    int i = blockIdx.x * 256 + threadIdx.x;
    if (i >= N) return;
    const float4* xr = reinterpret_cast<const float4*>(X + (size_t)i * K);
    float4 acc[16];
#pragma unroll
    for (int j = 0; j < 16; j++) acc[j] = make_float4(0.f, 0.f, 0.f, 0.f);
#pragma unroll 2
    for (int k4 = 0; k4 < K / 4; k4++) {
        float4 xv = xr[k4];
        const float* w0 = wl + k4 * 4 * 64;
#pragma unroll
        for (int j = 0; j < 16; j++) {
            float4 wa = reinterpret_cast<const float4*>(w0)[j];
            float4 wb = reinterpret_cast<const float4*>(w0 + 64)[j];
            float4 wc = reinterpret_cast<const float4*>(w0 + 128)[j];
            float4 wd = reinterpret_cast<const float4*>(w0 + 192)[j];
            acc[j].x += xv.x * wa.x + xv.y * wb.x + xv.z * wc.x + xv.w * wd.x;
            acc[j].y += xv.x * wa.y + xv.y * wb.y + xv.z * wc.y + xv.w * wd.y;
            acc[j].z += xv.x * wa.z + xv.y * wb.z + xv.z * wc.z + xv.w * wd.z;
            acc[j].w += xv.x * wa.w + xv.y * wb.w + xv.z * wc.w + xv.w * wd.w;
        }
    }
    float di = dinv[i];
    float4* op = reinterpret_cast<float4*>(out + (size_t)i * 64);
#pragma unroll
    for (int j = 0; j < 16; j++) {
        float4 v = acc[j];
        v.x *= di; v.y *= di; v.z *= di; v.w *= di;
        op[j] = v;
    }
}

// ---- agg[dst,:] += t[src,:]  (wave per edge, lane = feature) ----
__global__ __launch_bounds__(256) void scatter_kernel(const int* __restrict__ src,
                                                      const int* __restrict__ dst,
                                                      const float* __restrict__ t,
                                                      float* __restrict__ agg, int E) {
    int lane = threadIdx.x & 63;
    int wid = blockIdx.x * 4 + (threadIdx.x >> 6);
    int nw = gridDim.x * 4;
    for (int e = wid; e < E; e += nw) {
        int s = src[e], d = dst[e];
        float v = t[(size_t)s * 64 + lane];
        atomicAdd(&agg[(size_t)d * 64 + lane], v);
    }
}

// ---- h = relu(dinv[i]*agg + b) ----
__global__ void relu_bias_kernel(const float* __restrict__ agg, const float* __restrict__ dinv,
                                 const float* __restrict__ b, float* __restrict__ out, int N64) {
    int t = blockIdx.x * blockDim.x + threadIdx.x;
    if (t >= N64) return;
    int i = t >> 6, f = t & 63;
    float v = dinv[i] * agg[t] + b[f];
    out[t] = fmaxf(v, 0.0f);
}

// ---- per-node scalar s = dinv * (agg . Wl); segmented-sum into per-graph bins ----
// batch is SORTED: a 256-node chunk spans only 1-3 graphs -> LDS bins + tiny flush.
#define FINAL_CHUNK 256
__global__ __launch_bounds__(256) void final_kernel(const float* __restrict__ agg,
                                                    const float* __restrict__ dinv,
                                                    const float* __restrict__ Wl,
                                                    const int* __restrict__ batch,
                                                    float* __restrict__ gsum, int N) {
    __shared__ float bins[256];
    bins[threadIdx.x] = 0.0f;
    __syncthreads();
    int lane = threadIdx.x & 63;
    int w = threadIdx.x >> 6;
    int i0 = blockIdx.x * FINAL_CHUNK;
    int iend = min(i0 + FINAL_CHUNK, N);
    float wlv = Wl[lane];
    for (int i = i0 + w; i < iend; i += 4) {
        float p = agg[(size_t)i * 64 + lane] * wlv;
#pragma unroll
        for (int off = 32; off; off >>= 1) p += __shfl_down(p, off, 64);
        if (lane == 0) atomicAdd(&bins[batch[i]], dinv[i] * p);
    }
    __syncthreads();
    int gmin = batch[i0];
    int gmax = batch[iend - 1];
    for (int g = gmin + (int)threadIdx.x; g <= gmax; g += 256)
        atomicAdd(&gsum[g], bins[g]);
}

// ---- out[g] = gsum[g]/cnt[g] + dot(b2,Wl) + bl ; cnt via binary search on sorted batch ----
__global__ void out_kernel(const float* __restrict__ gsum, const int* __restrict__ batch,
                           const float* __restrict__ b2, const float* __restrict__ Wl,
                           const float* __restrict__ bl, float* __restrict__ out, int N) {
    int g = threadIdx.x;
    // lower_bound(batch, g) and lower_bound(batch, g+1)
    int lo = 0, hi = N;
    while (lo < hi) { int m = (lo + hi) >> 1; if (batch[m] < g) lo = m + 1; else hi = m; }
    int start = lo;
    hi = N;
    while (lo < hi) { int m = (lo + hi) >> 1; if (batch[m] < g + 1) lo = m + 1; else hi = m; }
    int cnt = lo - start;
    float c = 0.0f;
    for (int f = 0; f < 64; f++) c += b2[f] * Wl[f];
    out[g] = gsum[g] / fmaxf((float)cnt, 1.0f) + c + bl[0];
}

extern "C" void kernel_launch(void* const* d_in, const int* in_sizes, int n_in,
                              void* d_out, int out_size, void* d_ws, size_t ws_size,
                              hipStream_t stream) {
    const float* x  = (const float*)d_in[0];
    const int*   ei = (const int*)d_in[1];
    const int*   batch = (const int*)d_in[2];
    const float* W1 = (const float*)d_in[3];
    const float* b1 = (const float*)d_in[4];
    const float* W2 = (const float*)d_in[5];
    const float* b2 = (const float*)d_in[6];
    const float* Wl = (const float*)d_in[7];
    const float* bl = (const float*)d_in[8];
    float* out = (float*)d_out;

    const int N = N_NODES, E = N_EDGES;
    const int* src = ei;
    const int* dst = ei + E;

    float* wsf  = (float*)d_ws;
    float* dinv = wsf;                         // N floats (used as deg first)
    float* buf1 = wsf + 100096;                // N*64, 16B-aligned
    float* buf2 = buf1 + 6400000;              // N*64
    float* gsum = buf2 + 6400000;              // 256

    hipMemsetAsync(dinv, 0, N * sizeof(float), stream);
    hipMemsetAsync(gsum, 0, 256 * sizeof(float), stream);

    deg_kernel<<<(E + 255) / 256, 256, 0, stream>>>(dst, dinv, E);
    dinv_kernel<<<(N + 255) / 256, 256, 0, stream>>>(dinv, N);

    // Layer 1: t' = dinv*(x@W1); agg = t' (self loops); agg[dst]+=t'[src]; h1=relu(dinv*agg+b1)
    gemm_scale<128><<<(N + 255) / 256, 256, 0, stream>>>(x, W1, dinv, buf1, N);
    hipMemcpyAsync(buf2, buf1, (size_t)N * 64 * sizeof(float), hipMemcpyDeviceToDevice, stream);
    scatter_kernel<<<4096, 256, 0, stream>>>(src, dst, buf1, buf2, E);
    relu_bias_kernel<<<(N * 64 + 255) / 256, 256, 0, stream>>>(buf2, dinv, b1, buf1, N * 64);

    // Layer 2: t2' = dinv*(h1@W2); agg2 = t2'; agg2[dst]+=t2'[src]; epilogue folded into pool
    gemm_scale<64><<<(N + 255) / 256, 256, 0, stream>>>(buf1, W2, dinv, buf2, N);
    hipMemcpyAsync(buf1, buf2, (size_t)N * 64 * sizeof(float), hipMemcpyDeviceToDevice, stream);
    scatter_kernel<<<4096, 256, 0, stream>>>(src, dst, buf2, buf1, E);

    final_kernel<<<(N + FINAL_CHUNK - 1) / FINAL_CHUNK, 256, 0, stream>>>(buf1, dinv, Wl, batch, gsum, N);
    out_kernel<<<1, 256, 0, stream>>>(gsum, batch, b2, Wl, bl, out, N);
}

// Round 3
// 523.118 us; speedup vs baseline: 2.3716x; 1.5853x over previous
//
#include <hip/hip_runtime.h>

#define N_NODES 100000
#define N_EDGES 1200000

// ================= CSR build =================
__global__ void deg_kernel(const int* __restrict__ dst, int* __restrict__ deg, int E) {
    int e = blockIdx.x * blockDim.x + threadIdx.x;
    if (e < E) atomicAdd(&deg[dst[e]], 1);
}

__global__ void dinv_kernel(const int* __restrict__ deg, float* __restrict__ dinv, int N) {
    int i = blockIdx.x * blockDim.x + threadIdx.x;
    if (i < N) dinv[i] = rsqrtf((float)deg[i] + 1.0f);  // +1 = self loop
}

// block-level exclusive scan of deg -> row_start (local), block sums -> partial
__global__ __launch_bounds__(256) void scan1(const int* __restrict__ deg, int* __restrict__ row_start,
                                             int* __restrict__ partial, int N) {
    __shared__ int sh[256];
    int gid = blockIdx.x * 256 + threadIdx.x;
    int v = (gid < N) ? deg[gid] : 0;
    sh[threadIdx.x] = v;
    __syncthreads();
    for (int off = 1; off < 256; off <<= 1) {
        int t = (threadIdx.x >= off) ? sh[threadIdx.x - off] : 0;
        __syncthreads();
        sh[threadIdx.x] += t;
        __syncthreads();
    }
    if (gid < N) row_start[gid] = sh[threadIdx.x] - v;
    if (threadIdx.x == 255) partial[blockIdx.x] = sh[255];
}

// single-block exclusive scan of partials (nb <= 512)
__global__ __launch_bounds__(512) void scan2(int* __restrict__ partial, int nb) {
    __shared__ int sh[512];
    int v = (threadIdx.x < nb) ? partial[threadIdx.x] : 0;
    sh[threadIdx.x] = v;
    __syncthreads();
    for (int off = 1; off < 512; off <<= 1) {
        int t = (threadIdx.x >= off) ? sh[threadIdx.x - off] : 0;
        __syncthreads();
        sh[threadIdx.x] += t;
        __syncthreads();
    }
    if (threadIdx.x < nb) partial[threadIdx.x] = sh[threadIdx.x] - v;
}

__global__ void scan3(int* __restrict__ row_start, const int* __restrict__ partial,
                      int* __restrict__ pos, int N, int E) {
    int gid = blockIdx.x * blockDim.x + threadIdx.x;
    if (gid < N) {
        int v = row_start[gid] + partial[blockIdx.x * 256 / blockDim.x == 0 ? blockIdx.x : blockIdx.x];
        // (blockDim == 256 always; simple form below)
        v = row_start[gid] + partial[blockIdx.x];
        row_start[gid] = v;
        pos[gid] = v;
    }
    if (gid == 0) row_start[N] = E;
}

__global__ void edge_scatter(const int* __restrict__ src, const int* __restrict__ dst,
                             int* __restrict__ pos, int* __restrict__ csr, int E) {
    int e = blockIdx.x * blockDim.x + threadIdx.x;
    if (e < E) {
        int j = atomicAdd(&pos[dst[e]], 1);
        csr[j] = src[e];
    }
}

// ================= GEMM: out[i,:] = dinv[i] * (X[i,:] @ W) =================
template <int K>
__global__ __launch_bounds__(256) void gemm_scale(const float* __restrict__ X,
                                                  const float* __restrict__ W,
                                                  const float* __restrict__ dinv,
                                                  float* __restrict__ out, int N) {
    __shared__ float wl[K * 64];
    for (int idx = threadIdx.x; idx < K * 64; idx += 256) wl[idx] = W[idx];
    __syncthreads();
    int i = blockIdx.x * 256 + threadIdx.x;
    if (i >= N) return;
    const float4* xr = reinterpret_cast<const float4*>(X + (size_t)i * K);
    float4 acc[16];
#pragma unroll
    for (int j = 0; j < 16; j++) acc[j] = make_float4(0.f, 0.f, 0.f, 0.f);
#pragma unroll 2
    for (int k4 = 0; k4 < K / 4; k4++) {
        float4 xv = xr[k4];
        const float* w0 = wl + k4 * 4 * 64;
#pragma unroll
        for (int j = 0; j < 16; j++) {
            float4 wa = reinterpret_cast<const float4*>(w0)[j];
            float4 wb = reinterpret_cast<const float4*>(w0 + 64)[j];
            float4 wc = reinterpret_cast<const float4*>(w0 + 128)[j];
            float4 wd = reinterpret_cast<const float4*>(w0 + 192)[j];
            acc[j].x += xv.x * wa.x + xv.y * wb.x + xv.z * wc.x + xv.w * wd.x;
            acc[j].y += xv.x * wa.y + xv.y * wb.y + xv.z * wc.y + xv.w * wd.y;
            acc[j].z += xv.x * wa.z + xv.y * wb.z + xv.z * wc.z + xv.w * wd.z;
            acc[j].w += xv.x * wa.w + xv.y * wb.w + xv.z * wc.w + xv.w * wd.w;
        }
    }
    float di = dinv[i];
    float4* op = reinterpret_cast<float4*>(out + (size_t)i * 64);
#pragma unroll
    for (int j = 0; j < 16; j++) {
        float4 v = acc[j];
        v.x *= di; v.y *= di; v.z *= di; v.w *= di;
        op[j] = v;
    }
}

// ================= CSR aggregation, wave per node =================
// acc = t[i] (self loop) + sum_{j in row i} t[csr[j]]
// layer1: h[i] = relu(dinv[i]*acc + b1)           (LAYER2=false)
// layer2: p_i = dot(dinv[i]*acc, Wl) -> LDS bins by batch -> gsum atomics (LAYER2=true)
#define AGG_CHUNK 32
template <bool LAYER2>
__global__ __launch_bounds__(256) void agg_kernel(const float* __restrict__ t,
                                                  const int* __restrict__ row_start,
                                                  const int* __restrict__ csr,
                                                  const float* __restrict__ dinv,
                                                  const float* __restrict__ bvec,  // b1 or Wl
                                                  const int* __restrict__ batch,
                                                  float* __restrict__ out,  // h1 or gsum
                                                  int N) {
    __shared__ float bins[256];
    if (LAYER2) {
        bins[threadIdx.x] = 0.0f;
        __syncthreads();
    }
    int lane = threadIdx.x & 63;
    int w = threadIdx.x >> 6;
    int i0 = blockIdx.x * AGG_CHUNK;
    int iend = min(i0 + AGG_CHUNK, N);
    float bv = bvec[lane];
    for (int i = i0 + w; i < iend; i += 4) {
        int rs = row_start[i], re = row_start[i + 1];
        float acc = t[(size_t)i * 64 + lane];
        for (int base = rs; base < re; base += 64) {
            int m = re - base;
            int idx = (lane < m) ? csr[base + lane] : 0;
            int cnt = min(64, m);
            for (int k = 0; k < cnt; k++) {
                int s = __shfl(idx, k, 64);
                acc += t[(size_t)s * 64 + lane];
            }
        }
        if (!LAYER2) {
            out[(size_t)i * 64 + lane] = fmaxf(dinv[i] * acc + bv, 0.0f);
        } else {
            float p = dinv[i] * acc * bv;
#pragma unroll
            for (int off = 32; off; off >>= 1) p += __shfl_down(p, off, 64);
            if (lane == 0) atomicAdd(&bins[batch[i]], p);
        }
    }
    if (LAYER2) {
        __syncthreads();
        int gmin = batch[i0];
        int gmax = batch[iend - 1];
        for (int g = gmin + (int)threadIdx.x; g <= gmax; g += 256)
            atomicAdd(&out[g], bins[g]);
    }
}

// ---- out[g] = gsum[g]/cnt[g] + dot(b2,Wl) + bl ; cnt via binary search on sorted batch ----
__global__ void out_kernel(const float* __restrict__ gsum, const int* __restrict__ batch,
                           const float* __restrict__ b2, const float* __restrict__ Wl,
                           const float* __restrict__ bl, float* __restrict__ out, int N) {
    int g = threadIdx.x;
    int lo = 0, hi = N;
    while (lo < hi) { int m = (lo + hi) >> 1; if (batch[m] < g) lo = m + 1; else hi = m; }
    int start = lo;
    hi = N;
    while (lo < hi) { int m = (lo + hi) >> 1; if (batch[m] < g + 1) lo = m + 1; else hi = m; }
    int cnt = lo - start;
    float c = 0.0f;
    for (int f = 0; f < 64; f++) c += b2[f] * Wl[f];
    out[g] = gsum[g] / fmaxf((float)cnt, 1.0f) + c + bl[0];
}

extern "C" void kernel_launch(void* const* d_in, const int* in_sizes, int n_in,
                              void* d_out, int out_size, void* d_ws, size_t ws_size,
                              hipStream_t stream) {
    const float* x  = (const float*)d_in[0];
    const int*   ei = (const int*)d_in[1];
    const int*   batch = (const int*)d_in[2];
    const float* W1 = (const float*)d_in[3];
    const float* b1 = (const float*)d_in[4];
    const float* W2 = (const float*)d_in[5];
    const float* b2 = (const float*)d_in[6];
    const float* Wl = (const float*)d_in[7];
    const float* bl = (const float*)d_in[8];
    float* out = (float*)d_out;

    const int N = N_NODES, E = N_EDGES;
    const int nblk = (N + 255) / 256;  // 391
    const int* src = ei;
    const int* dst = ei + E;

    // workspace layout (4B units)
    char* ws = (char*)d_ws;
    float* dinv      = (float*)ws;                      ws += 100096 * 4;
    int*   deg_pos   = (int*)ws;                        ws += 100096 * 4;  // deg, later pos
    int*   row_start = (int*)ws;                        ws += 100112 * 4;  // N+1
    int*   partial   = (int*)ws;                        ws += 512 * 4;
    int*   csr       = (int*)ws;                        ws += 1200000 * 4;
    float* buf1      = (float*)ws;                      ws += 6400000 * 4;
    float* buf2      = (float*)ws;                      ws += 6400000 * 4;
    float* gsum      = (float*)ws;                      ws += 256 * 4;

    hipMemsetAsync(deg_pos, 0, N * sizeof(int), stream);
    hipMemsetAsync(gsum, 0, 256 * sizeof(float), stream);

    // CSR build (by dst) + dinv
    deg_kernel<<<(E + 255) / 256, 256, 0, stream>>>(dst, deg_pos, E);
    dinv_kernel<<<nblk, 256, 0, stream>>>(deg_pos, dinv, N);
    scan1<<<nblk, 256, 0, stream>>>(deg_pos, row_start, partial, N);
    scan2<<<1, 512, 0, stream>>>(partial, nblk);
    scan3<<<nblk, 256, 0, stream>>>(row_start, partial, deg_pos /*pos*/, N, E);
    edge_scatter<<<(E + 255) / 256, 256, 0, stream>>>(src, dst, deg_pos /*pos*/, csr, E);

    // Layer 1: t1 = dinv*(x@W1) ; h1 = relu(dinv*agg(t1) + b1)
    gemm_scale<128><<<nblk, 256, 0, stream>>>(x, W1, dinv, buf1, N);
    agg_kernel<false><<<(N + AGG_CHUNK - 1) / AGG_CHUNK, 256, 0, stream>>>(
        buf1, row_start, csr, dinv, b1, batch, buf2, N);

    // Layer 2: t2 = dinv*(h1@W2) ; pooled dot fused into aggregation
    gemm_scale<64><<<nblk, 256, 0, stream>>>(buf2, W2, dinv, buf1, N);
    agg_kernel<true><<<(N + AGG_CHUNK - 1) / AGG_CHUNK, 256, 0, stream>>>(
        buf1, row_start, csr, dinv, Wl, batch, gsum, N);

    out_kernel<<<1, 256, 0, stream>>>(gsum, batch, b2, Wl, bl, out, N);
}

// Round 4
// 365.988 us; speedup vs baseline: 3.3899x; 1.4293x over previous
//
#include <hip/hip_runtime.h>

#define N_NODES 100000
#define N_EDGES 1200000

// ================= CSR build =================
__global__ void deg_kernel(const int* __restrict__ dst, int* __restrict__ deg, int E) {
    int e = blockIdx.x * blockDim.x + threadIdx.x;
    if (e < E) atomicAdd(&deg[dst[e]], 1);
}

__global__ void dinv_kernel(const int* __restrict__ deg, float* __restrict__ dinv, int N) {
    int i = blockIdx.x * blockDim.x + threadIdx.x;
    if (i < N) dinv[i] = rsqrtf((float)deg[i] + 1.0f);  // +1 = self loop
}

__global__ __launch_bounds__(256) void scan1(const int* __restrict__ deg, int* __restrict__ row_start,
                                             int* __restrict__ partial, int N) {
    __shared__ int sh[256];
    int gid = blockIdx.x * 256 + threadIdx.x;
    int v = (gid < N) ? deg[gid] : 0;
    sh[threadIdx.x] = v;
    __syncthreads();
    for (int off = 1; off < 256; off <<= 1) {
        int t = (threadIdx.x >= off) ? sh[threadIdx.x - off] : 0;
        __syncthreads();
        sh[threadIdx.x] += t;
        __syncthreads();
    }
    if (gid < N) row_start[gid] = sh[threadIdx.x] - v;
    if (threadIdx.x == 255) partial[blockIdx.x] = sh[255];
}

__global__ __launch_bounds__(512) void scan2(int* __restrict__ partial, int nb) {
    __shared__ int sh[512];
    int v = (threadIdx.x < nb) ? partial[threadIdx.x] : 0;
    sh[threadIdx.x] = v;
    __syncthreads();
    for (int off = 1; off < 512; off <<= 1) {
        int t = (threadIdx.x >= off) ? sh[threadIdx.x - off] : 0;
        __syncthreads();
        sh[threadIdx.x] += t;
        __syncthreads();
    }
    if (threadIdx.x < nb) partial[threadIdx.x] = sh[threadIdx.x] - v;
}

__global__ void scan3(int* __restrict__ row_start, const int* __restrict__ partial,
                      int* __restrict__ pos, int N, int E) {
    int gid = blockIdx.x * blockDim.x + threadIdx.x;
    if (gid < N) {
        int v = row_start[gid] + partial[blockIdx.x];
        row_start[gid] = v;
        pos[gid] = v;
    }
    if (gid == 0) row_start[N] = E;
}

__global__ void edge_scatter(const int* __restrict__ src, const int* __restrict__ dst,
                             int* __restrict__ pos, int* __restrict__ csr, int E) {
    int e = blockIdx.x * blockDim.x + threadIdx.x;
    if (e < E) {
        int j = atomicAdd(&pos[dst[e]], 1);
        csr[j] = src[e];
    }
}

// ================= w2l = W2 @ Wl (fold layer-2 GEMM into a 64-vector) =================
__global__ void w2l_kernel(const float* __restrict__ W2, const float* __restrict__ Wl,
                           float* __restrict__ w2l) {
    int f = threadIdx.x;  // 64 threads
    float s = 0.0f;
    for (int o = 0; o < 64; o++) s += W2[f * 64 + o] * Wl[o];
    w2l[f] = s;
}

// ================= GEMM: out[i,:] = dinv[i] * (X[i,:] @ W1) =================
template <int K>
__global__ __launch_bounds__(256) void gemm_scale(const float* __restrict__ X,
                                                  const float* __restrict__ W,
                                                  const float* __restrict__ dinv,
                                                  float* __restrict__ out, int N) {
    __shared__ float wl[K * 64];
    for (int idx = threadIdx.x; idx < K * 64; idx += 256) wl[idx] = W[idx];
    __syncthreads();
    int i = blockIdx.x * 256 + threadIdx.x;
    if (i >= N) return;
    const float4* xr = reinterpret_cast<const float4*>(X + (size_t)i * K);
    float4 acc[16];
#pragma unroll
    for (int j = 0; j < 16; j++) acc[j] = make_float4(0.f, 0.f, 0.f, 0.f);
#pragma unroll 2
    for (int k4 = 0; k4 < K / 4; k4++) {
        float4 xv = xr[k4];
        const float* w0 = wl + k4 * 4 * 64;
#pragma unroll
        for (int j = 0; j < 16; j++) {
            float4 wa = reinterpret_cast<const float4*>(w0)[j];
            float4 wb = reinterpret_cast<const float4*>(w0 + 64)[j];
            float4 wc = reinterpret_cast<const float4*>(w0 + 128)[j];
            float4 wd = reinterpret_cast<const float4*>(w0 + 192)[j];
            acc[j].x += xv.x * wa.x + xv.y * wb.x + xv.z * wc.x + xv.w * wd.x;
            acc[j].y += xv.x * wa.y + xv.y * wb.y + xv.z * wc.y + xv.w * wd.y;
            acc[j].z += xv.x * wa.z + xv.y * wb.z + xv.z * wc.z + xv.w * wd.z;
            acc[j].w += xv.x * wa.w + xv.y * wb.w + xv.z * wc.w + xv.w * wd.w;
        }
    }
    float di = dinv[i];
    float4* op = reinterpret_cast<float4*>(out + (size_t)i * 64);
#pragma unroll
    for (int j = 0; j < 16; j++) {
        float4 v = acc[j];
        v.x *= di; v.y *= di; v.z *= di; v.w *= di;
        op[j] = v;
    }
}

// ================= Layer-1 CSR aggregation, wave per node, 4 edges in flight =================
// lane = (g4=edge group 0..3, f16=feature quad 0..15); each lane loads float4 -> one
// instruction gathers 4 rows. acc reduced over groups (xor16,32) BEFORE relu.
// Epilogue emits scalar q[i] = dinv[i] * dot(relu(dinv[i]*acc + b1), w2l). h1 never stored.
#define AGG_NPB 32
__global__ __launch_bounds__(256) void agg1_kernel(const float* __restrict__ t,
                                                   const int* __restrict__ row_start,
                                                   const int* __restrict__ csr,
                                                   const float* __restrict__ dinv,
                                                   const float* __restrict__ b1,
                                                   const float* __restrict__ w2l,
                                                   float* __restrict__ q, int N) {
    int lane = threadIdx.x & 63;
    int w = threadIdx.x >> 6;
    int g4 = lane >> 4;
    int f16 = lane & 15;
    float4 b1v = reinterpret_cast<const float4*>(b1)[f16];
    float4 wlv = reinterpret_cast<const float4*>(w2l)[f16];
    int i0 = blockIdx.x * AGG_NPB;
    int iend = min(i0 + AGG_NPB, N);
    for (int i = i0 + w; i < iend; i += 4) {
        int rs = row_start[i], re = row_start[i + 1];
        float4 acc = make_float4(0.f, 0.f, 0.f, 0.f);
        if (g4 == 0) acc = reinterpret_cast<const float4*>(t + (size_t)i * 64)[f16];  // self loop
        for (int base = rs; base < re; base += 64) {
            int m = re - base;
            int ecl = min(m, 64);
            int idx = csr[base + min(lane, m - 1)];  // pre-splat up to 64 edge ids
            for (int kb = 0; kb < ecl; kb += 4) {
                int s = __shfl(idx, kb + g4, 64);
                float4 v = reinterpret_cast<const float4*>(t + (size_t)s * 64)[f16];
                if (kb + g4 < ecl) {
                    acc.x += v.x; acc.y += v.y; acc.z += v.z; acc.w += v.w;
                }
            }
        }
        // reduce over the 4 edge-groups (f16 preserved under xor 16/32)
        acc.x += __shfl_xor(acc.x, 16, 64);
        acc.y += __shfl_xor(acc.y, 16, 64);
        acc.z += __shfl_xor(acc.z, 16, 64);
        acc.w += __shfl_xor(acc.w, 16, 64);
        acc.x += __shfl_xor(acc.x, 32, 64);
        acc.y += __shfl_xor(acc.y, 32, 64);
        acc.z += __shfl_xor(acc.z, 32, 64);
        acc.w += __shfl_xor(acc.w, 32, 64);
        float di = dinv[i];
        float hx = fmaxf(di * acc.x + b1v.x, 0.f);
        float hy = fmaxf(di * acc.y + b1v.y, 0.f);
        float hz = fmaxf(di * acc.z + b1v.z, 0.f);
        float hw = fmaxf(di * acc.w + b1v.w, 0.f);
        float p = hx * wlv.x + hy * wlv.y + hz * wlv.z + hw * wlv.w;
        p += __shfl_xor(p, 8, 64);
        p += __shfl_xor(p, 4, 64);
        p += __shfl_xor(p, 2, 64);
        p += __shfl_xor(p, 1, 64);
        if (lane == 0) q[i] = di * p;
    }
}

// ================= Layer-2 scalar agg + pooled sum (batch sorted -> LDS bins) =================
__global__ __launch_bounds__(256) void agg2_pool_kernel(const float* __restrict__ q,
                                                        const int* __restrict__ row_start,
                                                        const int* __restrict__ csr,
                                                        const float* __restrict__ dinv,
                                                        const int* __restrict__ batch,
                                                        float* __restrict__ gsum, int N) {
    __shared__ float bins[256];
    bins[threadIdx.x] = 0.0f;
    __syncthreads();
    int i = blockIdx.x * 256 + threadIdx.x;
    if (i < N) {
        int rs = row_start[i], re = row_start[i + 1];
        float acc = q[i];  // self loop
        for (int j = rs; j < re; j++) acc += q[csr[j]];
        atomicAdd(&bins[batch[i]], dinv[i] * acc);
    }
    __syncthreads();
    int i0 = blockIdx.x * 256;
    if (i0 < N) {
        int ilast = min(i0 + 255, N - 1);
        int gmin = batch[i0];
        int gmax = batch[ilast];
        for (int g = gmin + (int)threadIdx.x; g <= gmax; g += 256)
            atomicAdd(&gsum[g], bins[g]);
    }
}

// ---- out[g] = gsum[g]/cnt[g] + dot(b2,Wl) + bl ; cnt via binary search on sorted batch ----
__global__ void out_kernel(const float* __restrict__ gsum, const int* __restrict__ batch,
                           const float* __restrict__ b2, const float* __restrict__ Wl,
                           const float* __restrict__ bl, float* __restrict__ out, int N) {
    int g = threadIdx.x;
    int lo = 0, hi = N;
    while (lo < hi) { int m = (lo + hi) >> 1; if (batch[m] < g) lo = m + 1; else hi = m; }
    int start = lo;
    hi = N;
    while (lo < hi) { int m = (lo + hi) >> 1; if (batch[m] < g + 1) lo = m + 1; else hi = m; }
    int cnt = lo - start;
    float c = 0.0f;
    for (int f = 0; f < 64; f++) c += b2[f] * Wl[f];
    out[g] = gsum[g] / fmaxf((float)cnt, 1.0f) + c + bl[0];
}

extern "C" void kernel_launch(void* const* d_in, const int* in_sizes, int n_in,
                              void* d_out, int out_size, void* d_ws, size_t ws_size,
                              hipStream_t stream) {
    const float* x  = (const float*)d_in[0];
    const int*   ei = (const int*)d_in[1];
    const int*   batch = (const int*)d_in[2];
    const float* W1 = (const float*)d_in[3];
    const float* b1 = (const float*)d_in[4];
    const float* W2 = (const float*)d_in[5];
    const float* b2 = (const float*)d_in[6];
    const float* Wl = (const float*)d_in[7];
    const float* bl = (const float*)d_in[8];
    float* out = (float*)d_out;

    const int N = N_NODES, E = N_EDGES;
    const int nblk = (N + 255) / 256;  // 391
    const int* src = ei;
    const int* dst = ei + E;

    // workspace layout (bytes)
    char* ws = (char*)d_ws;
    float* dinv      = (float*)ws;  ws += 100096 * 4;
    int*   deg_pos   = (int*)ws;    ws += 100096 * 4;   // deg, later pos
    int*   row_start = (int*)ws;    ws += 100112 * 4;   // N+1
    int*   partial   = (int*)ws;    ws += 512 * 4;
    int*   csr       = (int*)ws;    ws += 1200128 * 4;
    float* buf1      = (float*)ws;  ws += 6400000 * 4;  // t1
    float* q         = (float*)ws;  ws += 100096 * 4;
    float* w2l       = (float*)ws;  ws += 256 * 4;
    float* gsum      = (float*)ws;  ws += 256 * 4;

    hipMemsetAsync(deg_pos, 0, N * sizeof(int), stream);
    hipMemsetAsync(gsum, 0, 256 * sizeof(float), stream);

    // CSR build (by dst) + dinv + folded layer-2 weight
    deg_kernel<<<(E + 255) / 256, 256, 0, stream>>>(dst, deg_pos, E);
    dinv_kernel<<<nblk, 256, 0, stream>>>(deg_pos, dinv, N);
    scan1<<<nblk, 256, 0, stream>>>(deg_pos, row_start, partial, N);
    scan2<<<1, 512, 0, stream>>>(partial, nblk);
    scan3<<<nblk, 256, 0, stream>>>(row_start, partial, deg_pos /*pos*/, N, E);
    edge_scatter<<<(E + 255) / 256, 256, 0, stream>>>(src, dst, deg_pos /*pos*/, csr, E);
    w2l_kernel<<<1, 64, 0, stream>>>(W2, Wl, w2l);

    // Layer 1 GEMM: t1 = dinv*(x@W1)
    gemm_scale<128><<<nblk, 256, 0, stream>>>(x, W1, dinv, buf1, N);

    // Layer-1 aggregation fused with layer-2 GEMM (as dot with w2l) -> scalar q per node
    agg1_kernel<<<(N + AGG_NPB - 1) / AGG_NPB, 256, 0, stream>>>(
        buf1, row_start, csr, dinv, b1, w2l, q, N);

    // Layer-2 scalar aggregation + mean-pool numerator
    agg2_pool_kernel<<<nblk, 256, 0, stream>>>(q, row_start, csr, dinv, batch, gsum, N);

    out_kernel<<<1, 256, 0, stream>>>(gsum, batch, b2, Wl, bl, out, N);
}

// Round 5
// 314.181 us; speedup vs baseline: 3.9488x; 1.1649x over previous
//
#include <hip/hip_runtime.h>

#define N_NODES 100000
#define N_EDGES 1200000
#define RANGE 12800          // 8 ranges cover 102400 >= N
#define SC_CHUNK 2048

// ================= CSR build =================
// Pass A: degree + slot ticket in one atomic
__global__ void deg_ticket_kernel(const int* __restrict__ dst, int* __restrict__ deg,
                                  int* __restrict__ ticket, int E) {
    int e = blockIdx.x * blockDim.x + threadIdx.x;
    if (e < E) ticket[e] = atomicAdd(&deg[dst[e]], 1);
}

__global__ void dinv_kernel(const int* __restrict__ deg, float* __restrict__ dinv, int N) {
    int i = blockIdx.x * blockDim.x + threadIdx.x;
    if (i < N) dinv[i] = rsqrtf((float)deg[i] + 1.0f);  // +1 = self loop
}

__global__ __launch_bounds__(256) void scan1(const int* __restrict__ deg, int* __restrict__ row_start,
                                             int* __restrict__ partial, int N) {
    __shared__ int sh[256];
    int gid = blockIdx.x * 256 + threadIdx.x;
    int v = (gid < N) ? deg[gid] : 0;
    sh[threadIdx.x] = v;
    __syncthreads();
    for (int off = 1; off < 256; off <<= 1) {
        int t = (threadIdx.x >= off) ? sh[threadIdx.x - off] : 0;
        __syncthreads();
        sh[threadIdx.x] += t;
        __syncthreads();
    }
    if (gid < N) row_start[gid] = sh[threadIdx.x] - v;
    if (threadIdx.x == 255) partial[blockIdx.x] = sh[255];
}

__global__ __launch_bounds__(512) void scan2(int* __restrict__ partial, int nb) {
    __shared__ int sh[512];
    int v = (threadIdx.x < nb) ? partial[threadIdx.x] : 0;
    sh[threadIdx.x] = v;
    __syncthreads();
    for (int off = 1; off < 512; off <<= 1) {
        int t = (threadIdx.x >= off) ? sh[threadIdx.x - off] : 0;
        __syncthreads();
        sh[threadIdx.x] += t;
        __syncthreads();
    }
    if (threadIdx.x < nb) partial[threadIdx.x] = sh[threadIdx.x] - v;
}

__global__ void scan3(int* __restrict__ row_start, const int* __restrict__ partial, int N, int E) {
    int gid = blockIdx.x * blockDim.x + threadIdx.x;
    if (gid < N) row_start[gid] += partial[blockIdx.x];
    if (gid == 0) row_start[N] = E;
}

// Pass C: XCD-local bucketed scatter. range = blockIdx&7 (round-robin -> one XCD per range),
// so all writes into a given csr slice come from one XCD's L2 -> full-line evictions.
__global__ __launch_bounds__(256) void csr_scatter(const int* __restrict__ src,
                                                   const int* __restrict__ dst,
                                                   const int* __restrict__ ticket,
                                                   const int* __restrict__ row_start,
                                                   int* __restrict__ csr, int E) {
    int r = blockIdx.x & 7;
    int c = blockIdx.x >> 3;
    int lo = r * RANGE, hi = lo + RANGE;
    int e0 = c * SC_CHUNK;
    int e1 = min(e0 + SC_CHUNK, E);
    for (int e = e0 + (int)threadIdx.x; e < e1; e += 256) {
        int d = dst[e];
        if (d >= lo && d < hi) {
            csr[row_start[d] + ticket[e]] = src[e];
        }
    }
}

// ================= w2l = W2 @ Wl =================
__global__ void w2l_kernel(const float* __restrict__ W2, const float* __restrict__ Wl,
                           float* __restrict__ w2l) {
    int f = threadIdx.x;  // 64 threads
    float s = 0.0f;
    for (int o = 0; o < 64; o++) s += W2[f * 64 + o] * Wl[o];
    w2l[f] = s;
}

// ================= GEMM: out[i,:] = dinv[i] * (X[i,:] @ W1) =================
template <int K>
__global__ __launch_bounds__(256) void gemm_scale(const float* __restrict__ X,
                                                  const float* __restrict__ W,
                                                  const float* __restrict__ dinv,
                                                  float* __restrict__ out, int N) {
    __shared__ float wl[K * 64];
    for (int idx = threadIdx.x; idx < K * 64; idx += 256) wl[idx] = W[idx];
    __syncthreads();
    int i = blockIdx.x * 256 + threadIdx.x;
    if (i >= N) return;
    const float4* xr = reinterpret_cast<const float4*>(X + (size_t)i * K);
    float4 acc[16];
#pragma unroll
    for (int j = 0; j < 16; j++) acc[j] = make_float4(0.f, 0.f, 0.f, 0.f);
#pragma unroll 2
    for (int k4 = 0; k4 < K / 4; k4++) {
        float4 xv = xr[k4];
        const float* w0 = wl + k4 * 4 * 64;
#pragma unroll
        for (int j = 0; j < 16; j++) {
            float4 wa = reinterpret_cast<const float4*>(w0)[j];
            float4 wb = reinterpret_cast<const float4*>(w0 + 64)[j];
            float4 wc = reinterpret_cast<const float4*>(w0 + 128)[j];
            float4 wd = reinterpret_cast<const float4*>(w0 + 192)[j];
            acc[j].x += xv.x * wa.x + xv.y * wb.x + xv.z * wc.x + xv.w * wd.x;
            acc[j].y += xv.x * wa.y + xv.y * wb.y + xv.z * wc.y + xv.w * wd.y;
            acc[j].z += xv.x * wa.z + xv.y * wb.z + xv.z * wc.z + xv.w * wd.z;
            acc[j].w += xv.x * wa.w + xv.y * wb.w + xv.z * wc.w + xv.w * wd.w;
        }
    }
    float di = dinv[i];
    float4* op = reinterpret_cast<float4*>(out + (size_t)i * 64);
#pragma unroll
    for (int j = 0; j < 16; j++) {
        float4 v = acc[j];
        v.x *= di; v.y *= di; v.z *= di; v.w *= di;
        op[j] = v;
    }
}

// ================= Layer-1 CSR agg, wave per node, 8 edges + 16 loads in flight =================
// lane = (g8 = edge group 0..7, f8 = feature octet 0..7); each lane loads 2 float4s
// (8 floats) of its edge's row -> 8 rows per iteration, 16 outstanding loads/lane.
// Epilogue: q[i] = dinv[i] * dot(relu(dinv[i]*acc + b1), w2l). h1 never materialized.
#define AGG_NPB 32
__global__ __launch_bounds__(256) void agg1_kernel(const float* __restrict__ t,
                                                   const int* __restrict__ row_start,
                                                   const int* __restrict__ csr,
                                                   const float* __restrict__ dinv,
                                                   const float* __restrict__ b1,
                                                   const float* __restrict__ w2l,
                                                   float* __restrict__ q, int N) {
    int lane = threadIdx.x & 63;
    int w = threadIdx.x >> 6;
    int g8 = lane >> 3;
    int f8 = lane & 7;
    float4 b1a = reinterpret_cast<const float4*>(b1)[f8 * 2];
    float4 b1b = reinterpret_cast<const float4*>(b1)[f8 * 2 + 1];
    float4 wla = reinterpret_cast<const float4*>(w2l)[f8 * 2];
    float4 wlb = reinterpret_cast<const float4*>(w2l)[f8 * 2 + 1];
    int i0 = blockIdx.x * AGG_NPB;
    int iend = min(i0 + AGG_NPB, N);
    for (int i = i0 + w; i < iend; i += 4) {
        int rs = row_start[i], re = row_start[i + 1];
        float4 a0 = make_float4(0.f, 0.f, 0.f, 0.f);
        float4 a1 = make_float4(0.f, 0.f, 0.f, 0.f);
        if (g8 == 0) {  // self loop
            const float4* sp = reinterpret_cast<const float4*>(t + (size_t)i * 64);
            a0 = sp[f8 * 2];
            a1 = sp[f8 * 2 + 1];
        }
        for (int base = rs; base < re; base += 64) {
            int m = re - base;
            int ecl = min(m, 64);
            int idx = csr[base + min(lane, m - 1)];  // splat up to 64 edge ids
            for (int kb = 0; kb < ecl; kb += 8) {
                int s = __shfl(idx, kb + g8, 64);
                const float4* rp = reinterpret_cast<const float4*>(t + (size_t)s * 64);
                float4 v0 = rp[f8 * 2];
                float4 v1 = rp[f8 * 2 + 1];
                if (kb + g8 < ecl) {
                    a0.x += v0.x; a0.y += v0.y; a0.z += v0.z; a0.w += v0.w;
                    a1.x += v1.x; a1.y += v1.y; a1.z += v1.z; a1.w += v1.w;
                }
            }
        }
        // reduce over the 8 edge-groups (f8 bits 0..2 preserved under xor 8/16/32)
#pragma unroll
        for (int off = 8; off <= 32; off <<= 1) {
            a0.x += __shfl_xor(a0.x, off, 64);
            a0.y += __shfl_xor(a0.y, off, 64);
            a0.z += __shfl_xor(a0.z, off, 64);
            a0.w += __shfl_xor(a0.w, off, 64);
            a1.x += __shfl_xor(a1.x, off, 64);
            a1.y += __shfl_xor(a1.y, off, 64);
            a1.z += __shfl_xor(a1.z, off, 64);
            a1.w += __shfl_xor(a1.w, off, 64);
        }
        float di = dinv[i];
        float p = fmaxf(di * a0.x + b1a.x, 0.f) * wla.x
                + fmaxf(di * a0.y + b1a.y, 0.f) * wla.y
                + fmaxf(di * a0.z + b1a.z, 0.f) * wla.z
                + fmaxf(di * a0.w + b1a.w, 0.f) * wla.w
                + fmaxf(di * a1.x + b1b.x, 0.f) * wlb.x
                + fmaxf(di * a1.y + b1b.y, 0.f) * wlb.y
                + fmaxf(di * a1.z + b1b.z, 0.f) * wlb.z
                + fmaxf(di * a1.w + b1b.w, 0.f) * wlb.w;
        p += __shfl_xor(p, 1, 64);
        p += __shfl_xor(p, 2, 64);
        p += __shfl_xor(p, 4, 64);
        if (lane == 0) q[i] = di * p;
    }
}

// ================= Layer-2 scalar agg + pooled sum (batch sorted -> LDS bins) =================
__global__ __launch_bounds__(256) void agg2_pool_kernel(const float* __restrict__ q,
                                                        const int* __restrict__ row_start,
                                                        const int* __restrict__ csr,
                                                        const float* __restrict__ dinv,
                                                        const int* __restrict__ batch,
                                                        float* __restrict__ gsum, int N) {
    __shared__ float bins[256];
    bins[threadIdx.x] = 0.0f;
    __syncthreads();
    int i = blockIdx.x * 256 + threadIdx.x;
    if (i < N) {
        int rs = row_start[i], re = row_start[i + 1];
        float acc = q[i];  // self loop
        for (int j = rs; j < re; j++) acc += q[csr[j]];
        atomicAdd(&bins[batch[i]], dinv[i] * acc);
    }
    __syncthreads();
    int i0 = blockIdx.x * 256;
    if (i0 < N) {
        int ilast = min(i0 + 255, N - 1);
        int gmin = batch[i0];
        int gmax = batch[ilast];
        for (int g = gmin + (int)threadIdx.x; g <= gmax; g += 256)
            atomicAdd(&gsum[g], bins[g]);
    }
}

// ---- out[g] = gsum[g]/cnt[g] + dot(b2,Wl) + bl ; cnt via binary search on sorted batch ----
__global__ void out_kernel(const float* __restrict__ gsum, const int* __restrict__ batch,
                           const float* __restrict__ b2, const float* __restrict__ Wl,
                           const float* __restrict__ bl, float* __restrict__ out, int N) {
    int g = threadIdx.x;
    int lo = 0, hi = N;
    while (lo < hi) { int m = (lo + hi) >> 1; if (batch[m] < g) lo = m + 1; else hi = m; }
    int start = lo;
    hi = N;
    while (lo < hi) { int m = (lo + hi) >> 1; if (batch[m] < g + 1) lo = m + 1; else hi = m; }
    int cnt = lo - start;
    float c = 0.0f;
    for (int f = 0; f < 64; f++) c += b2[f] * Wl[f];
    out[g] = gsum[g] / fmaxf((float)cnt, 1.0f) + c + bl[0];
}

extern "C" void kernel_launch(void* const* d_in, const int* in_sizes, int n_in,
                              void* d_out, int out_size, void* d_ws, size_t ws_size,
                              hipStream_t stream) {
    const float* x  = (const float*)d_in[0];
    const int*   ei = (const int*)d_in[1];
    const int*   batch = (const int*)d_in[2];
    const float* W1 = (const float*)d_in[3];
    const float* b1 = (const float*)d_in[4];
    const float* W2 = (const float*)d_in[5];
    const float* b2 = (const float*)d_in[6];
    const float* Wl = (const float*)d_in[7];
    const float* bl = (const float*)d_in[8];
    float* out = (float*)d_out;

    const int N = N_NODES, E = N_EDGES;
    const int nblk = (N + 255) / 256;  // 391
    const int* src = ei;
    const int* dst = ei + E;

    // workspace layout
    char* ws = (char*)d_ws;
    float* dinv      = (float*)ws;  ws += 100096 * 4;
    int*   deg       = (int*)ws;    ws += 100096 * 4;
    int*   row_start = (int*)ws;    ws += 100112 * 4;   // N+1
    int*   partial   = (int*)ws;    ws += 512 * 4;
    int*   csr       = (int*)ws;    ws += 1200128 * 4;
    int*   ticket    = (int*)ws;    ws += 1200128 * 4;
    float* buf1      = (float*)ws;  ws += 6400000 * 4;  // t1
    float* q         = (float*)ws;  ws += 100096 * 4;
    float* w2l       = (float*)ws;  ws += 256 * 4;
    float* gsum      = (float*)ws;  ws += 256 * 4;

    hipMemsetAsync(deg, 0, N * sizeof(int), stream);
    hipMemsetAsync(gsum, 0, 256 * sizeof(float), stream);

    // CSR build (by dst): ticket pass -> scan -> XCD-local bucketed scatter
    deg_ticket_kernel<<<(E + 255) / 256, 256, 0, stream>>>(dst, deg, ticket, E);
    dinv_kernel<<<nblk, 256, 0, stream>>>(deg, dinv, N);
    scan1<<<nblk, 256, 0, stream>>>(deg, row_start, partial, N);
    scan2<<<1, 512, 0, stream>>>(partial, nblk);
    scan3<<<nblk, 256, 0, stream>>>(row_start, partial, N, E);
    {
        int nchunk = (E + SC_CHUNK - 1) / SC_CHUNK;
        csr_scatter<<<nchunk * 8, 256, 0, stream>>>(src, dst, ticket, row_start, csr, E);
    }
    w2l_kernel<<<1, 64, 0, stream>>>(W2, Wl, w2l);

    // Layer 1 GEMM: t1 = dinv*(x@W1)
    gemm_scale<128><<<nblk, 256, 0, stream>>>(x, W1, dinv, buf1, N);

    // Layer-1 aggregation fused with folded layer-2 GEMM -> scalar q per node
    agg1_kernel<<<(N + AGG_NPB - 1) / AGG_NPB, 256, 0, stream>>>(
        buf1, row_start, csr, dinv, b1, w2l, q, N);

    // Layer-2 scalar aggregation + mean-pool numerator
    agg2_pool_kernel<<<nblk, 256, 0, stream>>>(q, row_start, csr, dinv, batch, gsum, N);

    out_kernel<<<1, 256, 0, stream>>>(gsum, batch, b2, Wl, bl, out, N);
}

// Round 6
// 301.925 us; speedup vs baseline: 4.1091x; 1.0406x over previous
//
#include <hip/hip_runtime.h>

#define N_NODES 100000
#define N_EDGES 1200000
#define RANGE 12800          // 8 ranges cover 102400 >= N
#define SC_CHUNK 2048

typedef _Float16 h8 __attribute__((ext_vector_type(8)));

// ================= CSR build =================
__global__ void deg_ticket_kernel(const int* __restrict__ dst, int* __restrict__ deg,
                                  int* __restrict__ ticket, int E) {
    int e = blockIdx.x * blockDim.x + threadIdx.x;
    if (e < E) ticket[e] = atomicAdd(&deg[dst[e]], 1);
}

__global__ void dinv_kernel(const int* __restrict__ deg, float* __restrict__ dinv, int N) {
    int i = blockIdx.x * blockDim.x + threadIdx.x;
    if (i < N) dinv[i] = rsqrtf((float)deg[i] + 1.0f);  // +1 = self loop
}

__global__ __launch_bounds__(256) void scan1(const int* __restrict__ deg, int* __restrict__ row_start,
                                             int* __restrict__ partial, int N) {
    __shared__ int sh[256];
    int gid = blockIdx.x * 256 + threadIdx.x;
    int v = (gid < N) ? deg[gid] : 0;
    sh[threadIdx.x] = v;
    __syncthreads();
    for (int off = 1; off < 256; off <<= 1) {
        int t = (threadIdx.x >= off) ? sh[threadIdx.x - off] : 0;
        __syncthreads();
        sh[threadIdx.x] += t;
        __syncthreads();
    }
    if (gid < N) row_start[gid] = sh[threadIdx.x] - v;
    if (threadIdx.x == 255) partial[blockIdx.x] = sh[255];
}

__global__ __launch_bounds__(512) void scan2(int* __restrict__ partial, int nb) {
    __shared__ int sh[512];
    int v = (threadIdx.x < nb) ? partial[threadIdx.x] : 0;
    sh[threadIdx.x] = v;
    __syncthreads();
    for (int off = 1; off < 512; off <<= 1) {
        int t = (threadIdx.x >= off) ? sh[threadIdx.x - off] : 0;
        __syncthreads();
        sh[threadIdx.x] += t;
        __syncthreads();
    }
    if (threadIdx.x < nb) partial[threadIdx.x] = sh[threadIdx.x] - v;
}

__global__ void scan3(int* __restrict__ row_start, const int* __restrict__ partial, int N, int E) {
    int gid = blockIdx.x * blockDim.x + threadIdx.x;
    if (gid < N) row_start[gid] += partial[blockIdx.x];
    if (gid == 0) row_start[N] = E;
}

// XCD-local bucketed scatter: range = blockIdx&7 -> one XCD per node-range
__global__ __launch_bounds__(256) void csr_scatter(const int* __restrict__ src,
                                                   const int* __restrict__ dst,
                                                   const int* __restrict__ ticket,
                                                   const int* __restrict__ row_start,
                                                   int* __restrict__ csr, int E) {
    int r = blockIdx.x & 7;
    int c = blockIdx.x >> 3;
    int lo = r * RANGE, hi = lo + RANGE;
    int e0 = c * SC_CHUNK;
    int e1 = min(e0 + SC_CHUNK, E);
    for (int e = e0 + (int)threadIdx.x; e < e1; e += 256) {
        int d = dst[e];
        if (d >= lo && d < hi) {
            csr[row_start[d] + ticket[e]] = src[e];
        }
    }
}

// ================= w2l = W2 @ Wl =================
__global__ void w2l_kernel(const float* __restrict__ W2, const float* __restrict__ Wl,
                           float* __restrict__ w2l) {
    int f = threadIdx.x;  // 64 threads
    float s = 0.0f;
    for (int o = 0; o < 64; o++) s += W2[f * 64 + o] * Wl[o];
    w2l[f] = s;
}

// ===== GEMM: t1[i,:] = fp16( dinv[i] * (X[i,:] @ W1) ), 2 nodes/thread (halve LDS reads) =====
template <int K>
__global__ __launch_bounds__(256) void gemm_scale_h(const float* __restrict__ X,
                                                    const float* __restrict__ W,
                                                    const float* __restrict__ dinv,
                                                    _Float16* __restrict__ out, int N) {
    __shared__ float wl[K * 64];
    for (int idx = threadIdx.x; idx < K * 64; idx += 256) wl[idx] = W[idx];
    __syncthreads();
    int i0 = blockIdx.x * 512 + threadIdx.x;
    int i1 = i0 + 256;
    int j0 = min(i0, N - 1), j1 = min(i1, N - 1);
    const float4* xr0 = reinterpret_cast<const float4*>(X + (size_t)j0 * K);
    const float4* xr1 = reinterpret_cast<const float4*>(X + (size_t)j1 * K);
    float4 acc0[16], acc1[16];
#pragma unroll
    for (int j = 0; j < 16; j++) {
        acc0[j] = make_float4(0.f, 0.f, 0.f, 0.f);
        acc1[j] = make_float4(0.f, 0.f, 0.f, 0.f);
    }
    for (int k4 = 0; k4 < K / 4; k4++) {
        float4 xa = xr0[k4];
        float4 xb = xr1[k4];
        const float* w0 = wl + k4 * 4 * 64;
#pragma unroll
        for (int j = 0; j < 16; j++) {
            float4 wa = reinterpret_cast<const float4*>(w0)[j];
            float4 wb = reinterpret_cast<const float4*>(w0 + 64)[j];
            float4 wc = reinterpret_cast<const float4*>(w0 + 128)[j];
            float4 wd = reinterpret_cast<const float4*>(w0 + 192)[j];
            acc0[j].x += xa.x * wa.x + xa.y * wb.x + xa.z * wc.x + xa.w * wd.x;
            acc0[j].y += xa.x * wa.y + xa.y * wb.y + xa.z * wc.y + xa.w * wd.y;
            acc0[j].z += xa.x * wa.z + xa.y * wb.z + xa.z * wc.z + xa.w * wd.z;
            acc0[j].w += xa.x * wa.w + xa.y * wb.w + xa.z * wc.w + xa.w * wd.w;
            acc1[j].x += xb.x * wa.x + xb.y * wb.x + xb.z * wc.x + xb.w * wd.x;
            acc1[j].y += xb.x * wa.y + xb.y * wb.y + xb.z * wc.y + xb.w * wd.y;
            acc1[j].z += xb.x * wa.z + xb.y * wb.z + xb.z * wc.z + xb.w * wd.z;
            acc1[j].w += xb.x * wa.w + xb.y * wb.w + xb.z * wc.w + xb.w * wd.w;
        }
    }
    if (i0 < N) {
        float di = dinv[j0];
        _Float16* op = out + (size_t)i0 * 64;
#pragma unroll
        for (int c = 0; c < 8; c++) {
            float4 a = acc0[c * 2], b = acc0[c * 2 + 1];
            h8 hv;
            hv[0] = (_Float16)(di * a.x); hv[1] = (_Float16)(di * a.y);
            hv[2] = (_Float16)(di * a.z); hv[3] = (_Float16)(di * a.w);
            hv[4] = (_Float16)(di * b.x); hv[5] = (_Float16)(di * b.y);
            hv[6] = (_Float16)(di * b.z); hv[7] = (_Float16)(di * b.w);
            *reinterpret_cast<h8*>(op + c * 8) = hv;
        }
    }
    if (i1 < N) {
        float di = dinv[j1];
        _Float16* op = out + (size_t)i1 * 64;
#pragma unroll
        for (int c = 0; c < 8; c++) {
            float4 a = acc1[c * 2], b = acc1[c * 2 + 1];
            h8 hv;
            hv[0] = (_Float16)(di * a.x); hv[1] = (_Float16)(di * a.y);
            hv[2] = (_Float16)(di * a.z); hv[3] = (_Float16)(di * a.w);
            hv[4] = (_Float16)(di * b.x); hv[5] = (_Float16)(di * b.y);
            hv[6] = (_Float16)(di * b.z); hv[7] = (_Float16)(di * b.w);
            *reinterpret_cast<h8*>(op + c * 8) = hv;
        }
    }
}

// ===== Layer-1 CSR agg over fp16 rows (128 B), wave/node, 8 edges in flight =====
// lane = (g8 = edge group 0..7, f8 = feature octet 0..7); each lane loads 8 halves (16B)
// -> 8 full rows per iteration. fp32 accumulate. Epilogue: q[i] = dinv*dot(relu(...), w2l).
#define AGG_NPB 32
__global__ __launch_bounds__(256) void agg1_kernel(const _Float16* __restrict__ t,
                                                   const int* __restrict__ row_start,
                                                   const int* __restrict__ csr,
                                                   const float* __restrict__ dinv,
                                                   const float* __restrict__ b1,
                                                   const float* __restrict__ w2l,
                                                   float* __restrict__ q, int N) {
    int lane = threadIdx.x & 63;
    int w = threadIdx.x >> 6;
    int g8 = lane >> 3;
    int f8 = lane & 7;
    float4 b1a = reinterpret_cast<const float4*>(b1)[f8 * 2];
    float4 b1b = reinterpret_cast<const float4*>(b1)[f8 * 2 + 1];
    float4 wla = reinterpret_cast<const float4*>(w2l)[f8 * 2];
    float4 wlb = reinterpret_cast<const float4*>(w2l)[f8 * 2 + 1];
    int i0 = blockIdx.x * AGG_NPB;
    int iend = min(i0 + AGG_NPB, N);
    for (int i = i0 + w; i < iend; i += 4) {
        int rs = row_start[i], re = row_start[i + 1];
        float4 a0 = make_float4(0.f, 0.f, 0.f, 0.f);
        float4 a1 = make_float4(0.f, 0.f, 0.f, 0.f);
        if (g8 == 0) {  // self loop
            h8 sv = *reinterpret_cast<const h8*>(t + (size_t)i * 64 + f8 * 8);
            a0.x = (float)sv[0]; a0.y = (float)sv[1]; a0.z = (float)sv[2]; a0.w = (float)sv[3];
            a1.x = (float)sv[4]; a1.y = (float)sv[5]; a1.z = (float)sv[6]; a1.w = (float)sv[7];
        }
        for (int base = rs; base < re; base += 64) {
            int m = re - base;
            int ecl = min(m, 64);
            int idx = csr[base + min(lane, m - 1)];  // splat up to 64 edge ids
            for (int kb = 0; kb < ecl; kb += 8) {
                int s = __shfl(idx, kb + g8, 64);
                h8 v = *reinterpret_cast<const h8*>(t + (size_t)s * 64 + f8 * 8);
                if (kb + g8 < ecl) {
                    a0.x += (float)v[0]; a0.y += (float)v[1];
                    a0.z += (float)v[2]; a0.w += (float)v[3];
                    a1.x += (float)v[4]; a1.y += (float)v[5];
                    a1.z += (float)v[6]; a1.w += (float)v[7];
                }
            }
        }
        // reduce over the 8 edge-groups (f8 bits preserved under xor 8/16/32)
#pragma unroll
        for (int off = 8; off <= 32; off <<= 1) {
            a0.x += __shfl_xor(a0.x, off, 64);
            a0.y += __shfl_xor(a0.y, off, 64);
            a0.z += __shfl_xor(a0.z, off, 64);
            a0.w += __shfl_xor(a0.w, off, 64);
            a1.x += __shfl_xor(a1.x, off, 64);
            a1.y += __shfl_xor(a1.y, off, 64);
            a1.z += __shfl_xor(a1.z, off, 64);
            a1.w += __shfl_xor(a1.w, off, 64);
        }
        float di = dinv[i];
        float p = fmaxf(di * a0.x + b1a.x, 0.f) * wla.x
                + fmaxf(di * a0.y + b1a.y, 0.f) * wla.y
                + fmaxf(di * a0.z + b1a.z, 0.f) * wla.z
                + fmaxf(di * a0.w + b1a.w, 0.f) * wla.w
                + fmaxf(di * a1.x + b1b.x, 0.f) * wlb.x
                + fmaxf(di * a1.y + b1b.y, 0.f) * wlb.y
                + fmaxf(di * a1.z + b1b.z, 0.f) * wlb.z
                + fmaxf(di * a1.w + b1b.w, 0.f) * wlb.w;
        p += __shfl_xor(p, 1, 64);
        p += __shfl_xor(p, 2, 64);
        p += __shfl_xor(p, 4, 64);
        if (lane == 0) q[i] = di * p;
    }
}

// ================= Layer-2 scalar agg + pooled sum (batch sorted -> LDS bins) =================
__global__ __launch_bounds__(256) void agg2_pool_kernel(const float* __restrict__ q,
                                                        const int* __restrict__ row_start,
                                                        const int* __restrict__ csr,
                                                        const float* __restrict__ dinv,
                                                        const int* __restrict__ batch,
                                                        float* __restrict__ gsum, int N) {
    __shared__ float bins[256];
    bins[threadIdx.x] = 0.0f;
    __syncthreads();
    int i = blockIdx.x * 256 + threadIdx.x;
    if (i < N) {
        int rs = row_start[i], re = row_start[i + 1];
        float acc = q[i];  // self loop
        for (int j = rs; j < re; j++) acc += q[csr[j]];
        atomicAdd(&bins[batch[i]], dinv[i] * acc);
    }
    __syncthreads();
    int i0 = blockIdx.x * 256;
    if (i0 < N) {
        int ilast = min(i0 + 255, N - 1);
        int gmin = batch[i0];
        int gmax = batch[ilast];
        for (int g = gmin + (int)threadIdx.x; g <= gmax; g += 256)
            atomicAdd(&gsum[g], bins[g]);
    }
}

// ---- out[g] = gsum[g]/cnt[g] + dot(b2,Wl) + bl ; cnt via binary search on sorted batch ----
__global__ void out_kernel(const float* __restrict__ gsum, const int* __restrict__ batch,
                           const float* __restrict__ b2, const float* __restrict__ Wl,
                           const float* __restrict__ bl, float* __restrict__ out, int N) {
    int g = threadIdx.x;
    int lo = 0, hi = N;
    while (lo < hi) { int m = (lo + hi) >> 1; if (batch[m] < g) lo = m + 1; else hi = m; }
    int start = lo;
    hi = N;
    while (lo < hi) { int m = (lo + hi) >> 1; if (batch[m] < g + 1) lo = m + 1; else hi = m; }
    int cnt = lo - start;
    float c = 0.0f;
    for (int f = 0; f < 64; f++) c += b2[f] * Wl[f];
    out[g] = gsum[g] / fmaxf((float)cnt, 1.0f) + c + bl[0];
}

extern "C" void kernel_launch(void* const* d_in, const int* in_sizes, int n_in,
                              void* d_out, int out_size, void* d_ws, size_t ws_size,
                              hipStream_t stream) {
    const float* x  = (const float*)d_in[0];
    const int*   ei = (const int*)d_in[1];
    const int*   batch = (const int*)d_in[2];
    const float* W1 = (const float*)d_in[3];
    const float* b1 = (const float*)d_in[4];
    const float* W2 = (const float*)d_in[5];
    const float* b2 = (const float*)d_in[6];
    const float* Wl = (const float*)d_in[7];
    const float* bl = (const float*)d_in[8];
    float* out = (float*)d_out;

    const int N = N_NODES, E = N_EDGES;
    const int nblk = (N + 255) / 256;  // 391
    const int* src = ei;
    const int* dst = ei + E;

    // workspace layout
    char* ws = (char*)d_ws;
    float*    dinv      = (float*)ws;     ws += 100096 * 4;
    int*      deg       = (int*)ws;       ws += 100096 * 4;
    int*      row_start = (int*)ws;       ws += 100112 * 4;   // N+1
    int*      partial   = (int*)ws;       ws += 512 * 4;
    int*      csr       = (int*)ws;       ws += 1200128 * 4;
    int*      ticket    = (int*)ws;       ws += 1200128 * 4;
    _Float16* buf1      = (_Float16*)ws;  ws += 6400000 * 2;  // t1 (fp16)
    ws += 128;                                               // align
    float*    q         = (float*)ws;     ws += 100096 * 4;
    float*    w2l       = (float*)ws;     ws += 256 * 4;
    float*    gsum      = (float*)ws;     ws += 256 * 4;

    hipMemsetAsync(deg, 0, N * sizeof(int), stream);
    hipMemsetAsync(gsum, 0, 256 * sizeof(float), stream);

    // CSR build (by dst): ticket pass -> scan -> XCD-local bucketed scatter
    deg_ticket_kernel<<<(E + 255) / 256, 256, 0, stream>>>(dst, deg, ticket, E);
    dinv_kernel<<<nblk, 256, 0, stream>>>(deg, dinv, N);
    scan1<<<nblk, 256, 0, stream>>>(deg, row_start, partial, N);
    scan2<<<1, 512, 0, stream>>>(partial, nblk);
    scan3<<<nblk, 256, 0, stream>>>(row_start, partial, N, E);
    {
        int nchunk = (E + SC_CHUNK - 1) / SC_CHUNK;
        csr_scatter<<<nchunk * 8, 256, 0, stream>>>(src, dst, ticket, row_start, csr, E);
    }
    w2l_kernel<<<1, 64, 0, stream>>>(W2, Wl, w2l);

    // Layer 1 GEMM: t1 = fp16(dinv*(x@W1)), 2 nodes/thread
    gemm_scale_h<128><<<(N + 511) / 512, 256, 0, stream>>>(x, W1, dinv, buf1, N);

    // Layer-1 aggregation fused with folded layer-2 GEMM -> scalar q per node
    agg1_kernel<<<(N + AGG_NPB - 1) / AGG_NPB, 256, 0, stream>>>(
        buf1, row_start, csr, dinv, b1, w2l, q, N);

    // Layer-2 scalar aggregation + mean-pool numerator
    agg2_pool_kernel<<<nblk, 256, 0, stream>>>(q, row_start, csr, dinv, batch, gsum, N);

    out_kernel<<<1, 256, 0, stream>>>(gsum, batch, b2, Wl, bl, out, N);
}

// Round 7
// 271.947 us; speedup vs baseline: 4.5621x; 1.1102x over previous
//
#include <hip/hip_runtime.h>

#define N_NODES 100000
#define N_EDGES 1200000
#define RANGE 12800          // 8 ranges cover 102400 >= N
#define SC_CHUNK 2048

typedef _Float16 h8 __attribute__((ext_vector_type(8)));
typedef float f32x16 __attribute__((ext_vector_type(16)));

// ================= CSR build =================
__global__ void deg_ticket_kernel(const int* __restrict__ dst, int* __restrict__ deg,
                                  int* __restrict__ ticket, int E) {
    int e = blockIdx.x * blockDim.x + threadIdx.x;
    if (e < E) ticket[e] = atomicAdd(&deg[dst[e]], 1);
}

__global__ void dinv_kernel(const int* __restrict__ deg, float* __restrict__ dinv, int N) {
    int i = blockIdx.x * blockDim.x + threadIdx.x;
    if (i < N) dinv[i] = rsqrtf((float)deg[i] + 1.0f);  // +1 = self loop
}

__global__ __launch_bounds__(256) void scan1(const int* __restrict__ deg, int* __restrict__ row_start,
                                             int* __restrict__ partial, int N) {
    __shared__ int sh[256];
    int gid = blockIdx.x * 256 + threadIdx.x;
    int v = (gid < N) ? deg[gid] : 0;
    sh[threadIdx.x] = v;
    __syncthreads();
    for (int off = 1; off < 256; off <<= 1) {
        int t = (threadIdx.x >= off) ? sh[threadIdx.x - off] : 0;
        __syncthreads();
        sh[threadIdx.x] += t;
        __syncthreads();
    }
    if (gid < N) row_start[gid] = sh[threadIdx.x] - v;
    if (threadIdx.x == 255) partial[blockIdx.x] = sh[255];
}

__global__ __launch_bounds__(512) void scan2(int* __restrict__ partial, int nb) {
    __shared__ int sh[512];
    int v = (threadIdx.x < nb) ? partial[threadIdx.x] : 0;
    sh[threadIdx.x] = v;
    __syncthreads();
    for (int off = 1; off < 512; off <<= 1) {
        int t = (threadIdx.x >= off) ? sh[threadIdx.x - off] : 0;
        __syncthreads();
        sh[threadIdx.x] += t;
        __syncthreads();
    }
    if (threadIdx.x < nb) partial[threadIdx.x] = sh[threadIdx.x] - v;
}

__global__ void scan3(int* __restrict__ row_start, const int* __restrict__ partial, int N, int E) {
    int gid = blockIdx.x * blockDim.x + threadIdx.x;
    if (gid < N) row_start[gid] += partial[blockIdx.x];
    if (gid == 0) row_start[N] = E;
}

// XCD-local bucketed scatter: range = blockIdx&7 -> one XCD per node-range
__global__ __launch_bounds__(256) void csr_scatter(const int* __restrict__ src,
                                                   const int* __restrict__ dst,
                                                   const int* __restrict__ ticket,
                                                   const int* __restrict__ row_start,
                                                   int* __restrict__ csr, int E) {
    int r = blockIdx.x & 7;
    int c = blockIdx.x >> 3;
    int lo = r * RANGE, hi = lo + RANGE;
    int e0 = c * SC_CHUNK;
    int e1 = min(e0 + SC_CHUNK, E);
    for (int e = e0 + (int)threadIdx.x; e < e1; e += 256) {
        int d = dst[e];
        if (d >= lo && d < hi) {
            csr[row_start[d] + ticket[e]] = src[e];
        }
    }
}

// ================= w2l = W2 @ Wl =================
__global__ void w2l_kernel(const float* __restrict__ W2, const float* __restrict__ Wl,
                           float* __restrict__ w2l) {
    int f = threadIdx.x;  // 64 threads
    float s = 0.0f;
    for (int o = 0; o < 64; o++) s += W2[f * 64 + o] * Wl[o];
    w2l[f] = s;
}

// ===== W1 -> split-fp16 B-fragments for mfma_f32_32x32x16_f16 =====
// layout: frag[((nt*8 + kk)*64 + lane)*8 + j] = W1[kk*16 + (lane>>5)*8 + j][nt*32 + (lane&31)]
__global__ void w1split_kernel(const float* __restrict__ W1, _Float16* __restrict__ whi,
                               _Float16* __restrict__ wlo) {
    int idx = blockIdx.x * 256 + threadIdx.x;  // 2*8*64*8 = 8192
    if (idx >= 8192) return;
    int j = idx & 7;
    int lane = (idx >> 3) & 63;
    int kk = (idx >> 9) & 7;
    int nt = idx >> 12;
    int k = kk * 16 + (lane >> 5) * 8 + j;
    int n = nt * 32 + (lane & 31);
    float v = W1[k * 64 + n];
    _Float16 hi = (_Float16)v;
    whi[idx] = hi;
    wlo[idx] = (_Float16)(v - (float)hi);
}

// ===== MFMA GEMM: t1[i,:] = fp16( dinv[i] * (X[i,:] @ W1) ) =====
// Split-fp16: x = ahi+alo, W1 = whi+wlo; acc += ahi*whi + ahi*wlo + alo*whi (fp32-accurate).
// Block = 128 nodes (4 waves); wave = 32 nodes x 64 cols (two 32x32 C tiles).
__global__ __launch_bounds__(256) void gemm_mfma(const float* __restrict__ x,
                                                 const _Float16* __restrict__ whi,
                                                 const _Float16* __restrict__ wlo,
                                                 const float* __restrict__ dinv,
                                                 _Float16* __restrict__ out, int N) {
    int wave = threadIdx.x >> 6;
    int lane = threadIdx.x & 63;
    int base = blockIdx.x * 128 + wave * 32;
    int row = base + (lane & 31);
    int rowc = min(row, N - 1);
    const float* xrow = x + (size_t)rowc * 128 + (lane >> 5) * 8;

    f32x16 acc0, acc1;
#pragma unroll
    for (int i = 0; i < 16; i++) { acc0[i] = 0.f; acc1[i] = 0.f; }

#pragma unroll
    for (int kk = 0; kk < 8; kk++) {
        float4 xa = *reinterpret_cast<const float4*>(xrow + kk * 16);
        float4 xb = *reinterpret_cast<const float4*>(xrow + kk * 16 + 4);
        float xv[8] = {xa.x, xa.y, xa.z, xa.w, xb.x, xb.y, xb.z, xb.w};
        h8 ahi, alo;
#pragma unroll
        for (int j = 0; j < 8; j++) {
            _Float16 hi = (_Float16)xv[j];
            ahi[j] = hi;
            alo[j] = (_Float16)(xv[j] - (float)hi);
        }
        h8 b0h = *reinterpret_cast<const h8*>(whi + (size_t)(kk * 64 + lane) * 8);
        h8 b0l = *reinterpret_cast<const h8*>(wlo + (size_t)(kk * 64 + lane) * 8);
        h8 b1h = *reinterpret_cast<const h8*>(whi + (size_t)((8 + kk) * 64 + lane) * 8);
        h8 b1l = *reinterpret_cast<const h8*>(wlo + (size_t)((8 + kk) * 64 + lane) * 8);
        acc0 = __builtin_amdgcn_mfma_f32_32x32x16_f16(ahi, b0h, acc0, 0, 0, 0);
        acc0 = __builtin_amdgcn_mfma_f32_32x32x16_f16(ahi, b0l, acc0, 0, 0, 0);
        acc0 = __builtin_amdgcn_mfma_f32_32x32x16_f16(alo, b0h, acc0, 0, 0, 0);
        acc1 = __builtin_amdgcn_mfma_f32_32x32x16_f16(ahi, b1h, acc1, 0, 0, 0);
        acc1 = __builtin_amdgcn_mfma_f32_32x32x16_f16(ahi, b1l, acc1, 0, 0, 0);
        acc1 = __builtin_amdgcn_mfma_f32_32x32x16_f16(alo, b1h, acc1, 0, 0, 0);
    }

    // C/D layout: col = lane&31, row = (reg&3) + 8*(reg>>2) + 4*(lane>>5)
    int col = lane & 31;
    int rbase = base + 4 * (lane >> 5);
#pragma unroll
    for (int reg = 0; reg < 16; reg++) {
        int node = rbase + (reg & 3) + 8 * (reg >> 2);
        if (node < N) {
            float di = dinv[node];
            out[(size_t)node * 64 + col] = (_Float16)(di * acc0[reg]);
            out[(size_t)node * 64 + 32 + col] = (_Float16)(di * acc1[reg]);
        }
    }
}

// ===== Layer-1 CSR agg over fp16 rows (128 B), wave/node, 8 edges in flight =====
#define AGG_NPB 32
__global__ __launch_bounds__(256) void agg1_kernel(const _Float16* __restrict__ t,
                                                   const int* __restrict__ row_start,
                                                   const int* __restrict__ csr,
                                                   const float* __restrict__ dinv,
                                                   const float* __restrict__ b1,
                                                   const float* __restrict__ w2l,
                                                   float* __restrict__ q, int N) {
    int lane = threadIdx.x & 63;
    int w = threadIdx.x >> 6;
    int g8 = lane >> 3;
    int f8 = lane & 7;
    float4 b1a = reinterpret_cast<const float4*>(b1)[f8 * 2];
    float4 b1b = reinterpret_cast<const float4*>(b1)[f8 * 2 + 1];
    float4 wla = reinterpret_cast<const float4*>(w2l)[f8 * 2];
    float4 wlb = reinterpret_cast<const float4*>(w2l)[f8 * 2 + 1];
    int i0 = blockIdx.x * AGG_NPB;
    int iend = min(i0 + AGG_NPB, N);
    for (int i = i0 + w; i < iend; i += 4) {
        int rs = row_start[i], re = row_start[i + 1];
        float4 a0 = make_float4(0.f, 0.f, 0.f, 0.f);
        float4 a1 = make_float4(0.f, 0.f, 0.f, 0.f);
        if (g8 == 0) {  // self loop
            h8 sv = *reinterpret_cast<const h8*>(t + (size_t)i * 64 + f8 * 8);
            a0.x = (float)sv[0]; a0.y = (float)sv[1]; a0.z = (float)sv[2]; a0.w = (float)sv[3];
            a1.x = (float)sv[4]; a1.y = (float)sv[5]; a1.z = (float)sv[6]; a1.w = (float)sv[7];
        }
        for (int base = rs; base < re; base += 64) {
            int m = re - base;
            int ecl = min(m, 64);
            int idx = csr[base + min(lane, m - 1)];  // splat up to 64 edge ids
            for (int kb = 0; kb < ecl; kb += 8) {
                int s = __shfl(idx, kb + g8, 64);
                h8 v = *reinterpret_cast<const h8*>(t + (size_t)s * 64 + f8 * 8);
                if (kb + g8 < ecl) {
                    a0.x += (float)v[0]; a0.y += (float)v[1];
                    a0.z += (float)v[2]; a0.w += (float)v[3];
                    a1.x += (float)v[4]; a1.y += (float)v[5];
                    a1.z += (float)v[6]; a1.w += (float)v[7];
                }
            }
        }
#pragma unroll
        for (int off = 8; off <= 32; off <<= 1) {
            a0.x += __shfl_xor(a0.x, off, 64);
            a0.y += __shfl_xor(a0.y, off, 64);
            a0.z += __shfl_xor(a0.z, off, 64);
            a0.w += __shfl_xor(a0.w, off, 64);
            a1.x += __shfl_xor(a1.x, off, 64);
            a1.y += __shfl_xor(a1.y, off, 64);
            a1.z += __shfl_xor(a1.z, off, 64);
            a1.w += __shfl_xor(a1.w, off, 64);
        }
        float di = dinv[i];
        float p = fmaxf(di * a0.x + b1a.x, 0.f) * wla.x
                + fmaxf(di * a0.y + b1a.y, 0.f) * wla.y
                + fmaxf(di * a0.z + b1a.z, 0.f) * wla.z
                + fmaxf(di * a0.w + b1a.w, 0.f) * wla.w
                + fmaxf(di * a1.x + b1b.x, 0.f) * wlb.x
                + fmaxf(di * a1.y + b1b.y, 0.f) * wlb.y
                + fmaxf(di * a1.z + b1b.z, 0.f) * wlb.z
                + fmaxf(di * a1.w + b1b.w, 0.f) * wlb.w;
        p += __shfl_xor(p, 1, 64);
        p += __shfl_xor(p, 2, 64);
        p += __shfl_xor(p, 4, 64);
        if (lane == 0) q[i] = di * p;
    }
}

// ================= Layer-2 scalar agg + pooled sum (batch sorted -> LDS bins) =================
__global__ __launch_bounds__(256) void agg2_pool_kernel(const float* __restrict__ q,
                                                        const int* __restrict__ row_start,
                                                        const int* __restrict__ csr,
                                                        const float* __restrict__ dinv,
                                                        const int* __restrict__ batch,
                                                        float* __restrict__ gsum, int N) {
    __shared__ float bins[256];
    bins[threadIdx.x] = 0.0f;
    __syncthreads();
    int i = blockIdx.x * 256 + threadIdx.x;
    if (i < N) {
        int rs = row_start[i], re = row_start[i + 1];
        float acc = q[i];  // self loop
        for (int j = rs; j < re; j++) acc += q[csr[j]];
        atomicAdd(&bins[batch[i]], dinv[i] * acc);
    }
    __syncthreads();
    int i0 = blockIdx.x * 256;
    if (i0 < N) {
        int ilast = min(i0 + 255, N - 1);
        int gmin = batch[i0];
        int gmax = batch[ilast];
        for (int g = gmin + (int)threadIdx.x; g <= gmax; g += 256)
            atomicAdd(&gsum[g], bins[g]);
    }
}

// ---- out[g] = gsum[g]/cnt[g] + dot(b2,Wl) + bl ; cnt via binary search on sorted batch ----
__global__ void out_kernel(const float* __restrict__ gsum, const int* __restrict__ batch,
                           const float* __restrict__ b2, const float* __restrict__ Wl,
                           const float* __restrict__ bl, float* __restrict__ out, int N) {
    int g = threadIdx.x;
    int lo = 0, hi = N;
    while (lo < hi) { int m = (lo + hi) >> 1; if (batch[m] < g) lo = m + 1; else hi = m; }
    int start = lo;
    hi = N;
    while (lo < hi) { int m = (lo + hi) >> 1; if (batch[m] < g + 1) lo = m + 1; else hi = m; }
    int cnt = lo - start;
    float c = 0.0f;
    for (int f = 0; f < 64; f++) c += b2[f] * Wl[f];
    out[g] = gsum[g] / fmaxf((float)cnt, 1.0f) + c + bl[0];
}

extern "C" void kernel_launch(void* const* d_in, const int* in_sizes, int n_in,
                              void* d_out, int out_size, void* d_ws, size_t ws_size,
                              hipStream_t stream) {
    const float* x  = (const float*)d_in[0];
    const int*   ei = (const int*)d_in[1];
    const int*   batch = (const int*)d_in[2];
    const float* W1 = (const float*)d_in[3];
    const float* b1 = (const float*)d_in[4];
    const float* W2 = (const float*)d_in[5];
    const float* b2 = (const float*)d_in[6];
    const float* Wl = (const float*)d_in[7];
    const float* bl = (const float*)d_in[8];
    float* out = (float*)d_out;

    const int N = N_NODES, E = N_EDGES;
    const int nblk = (N + 255) / 256;  // 391
    const int* src = ei;
    const int* dst = ei + E;

    // workspace layout
    char* ws = (char*)d_ws;
    float*    dinv      = (float*)ws;     ws += 100096 * 4;
    int*      deg       = (int*)ws;       ws += 100096 * 4;
    int*      row_start = (int*)ws;       ws += 100112 * 4;   // N+1
    int*      partial   = (int*)ws;       ws += 512 * 4;
    int*      csr       = (int*)ws;       ws += 1200128 * 4;
    int*      ticket    = (int*)ws;       ws += 1200128 * 4;
    _Float16* buf1      = (_Float16*)ws;  ws += 6400000 * 2;  // t1 (fp16)
    ws += 128;                                               // align
    float*    q         = (float*)ws;     ws += 100096 * 4;
    float*    w2l       = (float*)ws;     ws += 256 * 4;
    float*    gsum      = (float*)ws;     ws += 256 * 4;
    _Float16* whi       = (_Float16*)ws;  ws += 8192 * 2;
    _Float16* wlo       = (_Float16*)ws;  ws += 8192 * 2;

    hipMemsetAsync(deg, 0, N * sizeof(int), stream);
    hipMemsetAsync(gsum, 0, 256 * sizeof(float), stream);

    // CSR build (by dst): ticket pass -> scan -> XCD-local bucketed scatter
    deg_ticket_kernel<<<(E + 255) / 256, 256, 0, stream>>>(dst, deg, ticket, E);
    dinv_kernel<<<nblk, 256, 0, stream>>>(deg, dinv, N);
    scan1<<<nblk, 256, 0, stream>>>(deg, row_start, partial, N);
    scan2<<<1, 512, 0, stream>>>(partial, nblk);
    scan3<<<nblk, 256, 0, stream>>>(row_start, partial, N, E);
    {
        int nchunk = (E + SC_CHUNK - 1) / SC_CHUNK;
        csr_scatter<<<nchunk * 8, 256, 0, stream>>>(src, dst, ticket, row_start, csr, E);
    }
    w2l_kernel<<<1, 64, 0, stream>>>(W2, Wl, w2l);
    w1split_kernel<<<32, 256, 0, stream>>>(W1, whi, wlo);

    // Layer 1 GEMM on matrix cores: t1 = fp16(dinv*(x@W1)), split-fp16 for fp32 accuracy
    gemm_mfma<<<(N + 127) / 128, 256, 0, stream>>>(x, whi, wlo, dinv, buf1, N);

    // Layer-1 aggregation fused with folded layer-2 GEMM -> scalar q per node
    agg1_kernel<<<(N + AGG_NPB - 1) / AGG_NPB, 256, 0, stream>>>(
        buf1, row_start, csr, dinv, b1, w2l, q, N);

    // Layer-2 scalar aggregation + mean-pool numerator
    agg2_pool_kernel<<<nblk, 256, 0, stream>>>(q, row_start, csr, dinv, batch, gsum, N);

    out_kernel<<<1, 256, 0, stream>>>(gsum, batch, b2, Wl, bl, out, N);
}

// Round 8
// 261.960 us; speedup vs baseline: 4.7360x; 1.0381x over previous
//
#include <hip/hip_runtime.h>

#define N_NODES 100000
#define N_EDGES 1200000
#define R_BUCKETS 64
#define RSZ 1600             // 64 * 1600 = 102400 >= N
#define CH 4096
#define NC 293               // ceil(1200000 / 4096)

typedef _Float16 h8 __attribute__((ext_vector_type(8)));
typedef float f32x16 __attribute__((ext_vector_type(16)));

// ================= CSR build, atomic-free (LDS-local only) =================
// B1: per-chunk 64-bucket histogram
__global__ __launch_bounds__(256) void bkt_count(const int* __restrict__ dst,
                                                 int* __restrict__ cnt, int E) {
    __shared__ int h[R_BUCKETS];
    if (threadIdx.x < R_BUCKETS) h[threadIdx.x] = 0;
    __syncthreads();
    int e0 = blockIdx.x * CH;
    int e1 = min(e0 + CH, E);
    for (int e = e0 + (int)threadIdx.x; e < e1; e += 256)
        atomicAdd(&h[dst[e] / RSZ], 1);
    __syncthreads();
    if (threadIdx.x < R_BUCKETS) cnt[blockIdx.x * R_BUCKETS + threadIdx.x] = h[threadIdx.x];
}

// B2: exclusive scan over s = r*NC + c of cnt[c][r] -> boff; bucket_base[r] = boff at c=0
__global__ __launch_bounds__(1024) void bkt_offsets(const int* __restrict__ cnt,
                                                    int* __restrict__ boff,
                                                    int* __restrict__ bucket_base, int E) {
    const int TOT = R_BUCKETS * NC;           // 18752
    const int PER = (TOT + 1023) / 1024;      // 19
    __shared__ int part[1024];
    int t = threadIdx.x;
    int s0 = t * PER;
    int sum = 0;
    for (int k = 0; k < PER; k++) {
        int s = s0 + k;
        if (s < TOT) {
            int r = s / NC, c = s - r * NC;
            sum += cnt[c * R_BUCKETS + r];
        }
    }
    part[t] = sum;
    __syncthreads();
    for (int off = 1; off < 1024; off <<= 1) {
        int v = (t >= off) ? part[t - off] : 0;
        __syncthreads();
        part[t] += v;
        __syncthreads();
    }
    int run = part[t] - sum;  // exclusive
    for (int k = 0; k < PER; k++) {
        int s = s0 + k;
        if (s < TOT) {
            int r = s / NC, c = s - r * NC;
            boff[s] = run;
            if (c == 0) bucket_base[r] = run;
            run += cnt[c * R_BUCKETS + r];
        }
    }
    if (t == 0) bucket_base[R_BUCKETS] = E;
}

// B3: bucket-scatter edges into ebuf (ticket order arbitrary -> LDS counters only)
__global__ __launch_bounds__(256) void bkt_scatter(const int* __restrict__ src,
                                                   const int* __restrict__ dst,
                                                   const int* __restrict__ boff,
                                                   int2* __restrict__ ebuf, int E) {
    __shared__ int off[R_BUCKETS];
    if (threadIdx.x < R_BUCKETS) off[threadIdx.x] = boff[threadIdx.x * NC + blockIdx.x];
    __syncthreads();
    int e0 = blockIdx.x * CH;
    int e1 = min(e0 + CH, E);
    for (int e = e0 + (int)threadIdx.x; e < e1; e += 256) {
        int d = dst[e];
        int p = atomicAdd(&off[d / RSZ], 1);
        ebuf[p] = make_int2(src[e], d);
    }
}

// B4: per-bucket: LDS histogram -> deg/dinv, LDS scan -> row_start, pass2 -> csr
__global__ __launch_bounds__(512) void bkt_build(const int2* __restrict__ ebuf,
                                                 const int* __restrict__ bucket_base,
                                                 int* __restrict__ row_start,
                                                 float* __restrict__ dinv,
                                                 int* __restrict__ csr, int N, int E) {
    __shared__ int hist[RSZ];
    __shared__ int pref[RSZ];
    __shared__ int part[512];
    int r = blockIdx.x;
    int nbase = r * RSZ;
    int ebase = bucket_base[r];
    int eend = bucket_base[r + 1];
    for (int i = threadIdx.x; i < RSZ; i += 512) hist[i] = 0;
    __syncthreads();
#pragma unroll 4
    for (int e = ebase + (int)threadIdx.x; e < eend; e += 512)
        atomicAdd(&hist[ebuf[e].y - nbase], 1);
    __syncthreads();
    for (int i = threadIdx.x; i < RSZ; i += 512) {
        int gi = nbase + i;
        if (gi < N) dinv[gi] = rsqrtf((float)hist[i] + 1.0f);  // +1 self loop
    }
    // exclusive scan hist -> pref (4 bins/thread)
    int s0 = threadIdx.x * 4;
    int sum = 0;
#pragma unroll
    for (int k = 0; k < 4; k++) { int s = s0 + k; if (s < RSZ) sum += hist[s]; }
    part[threadIdx.x] = sum;
    __syncthreads();
    for (int off = 1; off < 512; off <<= 1) {
        int v = (threadIdx.x >= off) ? part[threadIdx.x - off] : 0;
        __syncthreads();
        part[threadIdx.x] += v;
        __syncthreads();
    }
    int run = part[threadIdx.x] - sum;
#pragma unroll
    for (int k = 0; k < 4; k++) {
        int s = s0 + k;
        if (s < RSZ) { pref[s] = run; run += hist[s]; }
    }
    __syncthreads();
    for (int i = threadIdx.x; i < RSZ; i += 512) {
        int gi = nbase + i;
        if (gi <= N) row_start[gi] = ebase + pref[i];
    }
    // pass 2: ticket via LDS counters starting at pref
    for (int i = threadIdx.x; i < RSZ; i += 512) hist[i] = pref[i];
    __syncthreads();
#pragma unroll 4
    for (int e = ebase + (int)threadIdx.x; e < eend; e += 512) {
        int2 sd = ebuf[e];
        int t = atomicAdd(&hist[sd.y - nbase], 1);
        csr[ebase + t] = sd.x;
    }
}

// ================= w2l = W2 @ Wl =================
__global__ void w2l_kernel(const float* __restrict__ W2, const float* __restrict__ Wl,
                           float* __restrict__ w2l) {
    int f = threadIdx.x;  // 64 threads
    float s = 0.0f;
    for (int o = 0; o < 64; o++) s += W2[f * 64 + o] * Wl[o];
    w2l[f] = s;
}

// ===== W1 -> split-fp16 B-fragments for mfma_f32_32x32x16_f16 =====
__global__ void w1split_kernel(const float* __restrict__ W1, _Float16* __restrict__ whi,
                               _Float16* __restrict__ wlo) {
    int idx = blockIdx.x * 256 + threadIdx.x;  // 2*8*64*8 = 8192
    if (idx >= 8192) return;
    int j = idx & 7;
    int lane = (idx >> 3) & 63;
    int kk = (idx >> 9) & 7;
    int nt = idx >> 12;
    int k = kk * 16 + (lane >> 5) * 8 + j;
    int n = nt * 32 + (lane & 31);
    float v = W1[k * 64 + n];
    _Float16 hi = (_Float16)v;
    whi[idx] = hi;
    wlo[idx] = (_Float16)(v - (float)hi);
}

// ===== MFMA GEMM: t1[i,:] = fp16( dinv[i] * (X[i,:] @ W1) ), split-fp16 accuracy =====
__global__ __launch_bounds__(256) void gemm_mfma(const float* __restrict__ x,
                                                 const _Float16* __restrict__ whi,
                                                 const _Float16* __restrict__ wlo,
                                                 const float* __restrict__ dinv,
                                                 _Float16* __restrict__ out, int N) {
    int wave = threadIdx.x >> 6;
    int lane = threadIdx.x & 63;
    int base = blockIdx.x * 128 + wave * 32;
    int row = base + (lane & 31);
    int rowc = min(row, N - 1);
    const float* xrow = x + (size_t)rowc * 128 + (lane >> 5) * 8;

    f32x16 acc0, acc1;
#pragma unroll
    for (int i = 0; i < 16; i++) { acc0[i] = 0.f; acc1[i] = 0.f; }

#pragma unroll
    for (int kk = 0; kk < 8; kk++) {
        float4 xa = *reinterpret_cast<const float4*>(xrow + kk * 16);
        float4 xb = *reinterpret_cast<const float4*>(xrow + kk * 16 + 4);
        float xv[8] = {xa.x, xa.y, xa.z, xa.w, xb.x, xb.y, xb.z, xb.w};
        h8 ahi, alo;
#pragma unroll
        for (int j = 0; j < 8; j++) {
            _Float16 hi = (_Float16)xv[j];
            ahi[j] = hi;
            alo[j] = (_Float16)(xv[j] - (float)hi);
        }
        h8 b0h = *reinterpret_cast<const h8*>(whi + (size_t)(kk * 64 + lane) * 8);
        h8 b0l = *reinterpret_cast<const h8*>(wlo + (size_t)(kk * 64 + lane) * 8);
        h8 b1h = *reinterpret_cast<const h8*>(whi + (size_t)((8 + kk) * 64 + lane) * 8);
        h8 b1l = *reinterpret_cast<const h8*>(wlo + (size_t)((8 + kk) * 64 + lane) * 8);
        acc0 = __builtin_amdgcn_mfma_f32_32x32x16_f16(ahi, b0h, acc0, 0, 0, 0);
        acc0 = __builtin_amdgcn_mfma_f32_32x32x16_f16(ahi, b0l, acc0, 0, 0, 0);
        acc0 = __builtin_amdgcn_mfma_f32_32x32x16_f16(alo, b0h, acc0, 0, 0, 0);
        acc1 = __builtin_amdgcn_mfma_f32_32x32x16_f16(ahi, b1h, acc1, 0, 0, 0);
        acc1 = __builtin_amdgcn_mfma_f32_32x32x16_f16(ahi, b1l, acc1, 0, 0, 0);
        acc1 = __builtin_amdgcn_mfma_f32_32x32x16_f16(alo, b1h, acc1, 0, 0, 0);
    }

    // C/D layout: col = lane&31, row = (reg&3) + 8*(reg>>2) + 4*(lane>>5)
    int col = lane & 31;
    int rbase = base + 4 * (lane >> 5);
#pragma unroll
    for (int reg = 0; reg < 16; reg++) {
        int node = rbase + (reg & 3) + 8 * (reg >> 2);
        if (node < N) {
            float di = dinv[node];
            out[(size_t)node * 64 + col] = (_Float16)(di * acc0[reg]);
            out[(size_t)node * 64 + 32 + col] = (_Float16)(di * acc1[reg]);
        }
    }
}

// ===== Layer-1 CSR agg over fp16 rows (128 B), wave/node, 8 edges in flight =====
#define AGG_NPB 32
__global__ __launch_bounds__(256) void agg1_kernel(const _Float16* __restrict__ t,
                                                   const int* __restrict__ row_start,
                                                   const int* __restrict__ csr,
                                                   const float* __restrict__ dinv,
                                                   const float* __restrict__ b1,
                                                   const float* __restrict__ w2l,
                                                   float* __restrict__ q, int N) {
    int lane = threadIdx.x & 63;
    int w = threadIdx.x >> 6;
    int g8 = lane >> 3;
    int f8 = lane & 7;
    float4 b1a = reinterpret_cast<const float4*>(b1)[f8 * 2];
    float4 b1b = reinterpret_cast<const float4*>(b1)[f8 * 2 + 1];
    float4 wla = reinterpret_cast<const float4*>(w2l)[f8 * 2];
    float4 wlb = reinterpret_cast<const float4*>(w2l)[f8 * 2 + 1];
    int i0 = blockIdx.x * AGG_NPB;
    int iend = min(i0 + AGG_NPB, N);
    for (int i = i0 + w; i < iend; i += 4) {
        int rs = row_start[i], re = row_start[i + 1];
        float4 a0 = make_float4(0.f, 0.f, 0.f, 0.f);
        float4 a1 = make_float4(0.f, 0.f, 0.f, 0.f);
        if (g8 == 0) {  // self loop
            h8 sv = *reinterpret_cast<const h8*>(t + (size_t)i * 64 + f8 * 8);
            a0.x = (float)sv[0]; a0.y = (float)sv[1]; a0.z = (float)sv[2]; a0.w = (float)sv[3];
            a1.x = (float)sv[4]; a1.y = (float)sv[5]; a1.z = (float)sv[6]; a1.w = (float)sv[7];
        }
        for (int base = rs; base < re; base += 64) {
            int m = re - base;
            int ecl = min(m, 64);
            int idx = csr[base + min(lane, m - 1)];  // splat up to 64 edge ids
            for (int kb = 0; kb < ecl; kb += 8) {
                int s = __shfl(idx, kb + g8, 64);
                h8 v = *reinterpret_cast<const h8*>(t + (size_t)s * 64 + f8 * 8);
                if (kb + g8 < ecl) {
                    a0.x += (float)v[0]; a0.y += (float)v[1];
                    a0.z += (float)v[2]; a0.w += (float)v[3];
                    a1.x += (float)v[4]; a1.y += (float)v[5];
                    a1.z += (float)v[6]; a1.w += (float)v[7];
                }
            }
        }
#pragma unroll
        for (int off = 8; off <= 32; off <<= 1) {
            a0.x += __shfl_xor(a0.x, off, 64);
            a0.y += __shfl_xor(a0.y, off, 64);
            a0.z += __shfl_xor(a0.z, off, 64);
            a0.w += __shfl_xor(a0.w, off, 64);
            a1.x += __shfl_xor(a1.x, off, 64);
            a1.y += __shfl_xor(a1.y, off, 64);
            a1.z += __shfl_xor(a1.z, off, 64);
            a1.w += __shfl_xor(a1.w, off, 64);
        }
        float di = dinv[i];
        float p = fmaxf(di * a0.x + b1a.x, 0.f) * wla.x
                + fmaxf(di * a0.y + b1a.y, 0.f) * wla.y
                + fmaxf(di * a0.z + b1a.z, 0.f) * wla.z
                + fmaxf(di * a0.w + b1a.w, 0.f) * wla.w
                + fmaxf(di * a1.x + b1b.x, 0.f) * wlb.x
                + fmaxf(di * a1.y + b1b.y, 0.f) * wlb.y
                + fmaxf(di * a1.z + b1b.z, 0.f) * wlb.z
                + fmaxf(di * a1.w + b1b.w, 0.f) * wlb.w;
        p += __shfl_xor(p, 1, 64);
        p += __shfl_xor(p, 2, 64);
        p += __shfl_xor(p, 4, 64);
        if (lane == 0) q[i] = di * p;
    }
}

// ================= Layer-2 scalar agg + pooled sum (batch sorted -> LDS bins) =================
__global__ __launch_bounds__(256) void agg2_pool_kernel(const float* __restrict__ q,
                                                        const int* __restrict__ row_start,
                                                        const int* __restrict__ csr,
                                                        const float* __restrict__ dinv,
                                                        const int* __restrict__ batch,
                                                        float* __restrict__ gsum, int N) {
    __shared__ float bins[256];
    bins[threadIdx.x] = 0.0f;
    __syncthreads();
    int i = blockIdx.x * 256 + threadIdx.x;
    if (i < N) {
        int rs = row_start[i], re = row_start[i + 1];
        float acc = q[i];  // self loop
        for (int j = rs; j < re; j++) acc += q[csr[j]];
        atomicAdd(&bins[batch[i]], dinv[i] * acc);
    }
    __syncthreads();
    int i0 = blockIdx.x * 256;
    if (i0 < N) {
        int ilast = min(i0 + 255, N - 1);
        int gmin = batch[i0];
        int gmax = batch[ilast];
        for (int g = gmin + (int)threadIdx.x; g <= gmax; g += 256)
            atomicAdd(&gsum[g], bins[g]);
    }
}

// ---- out[g] = gsum[g]/cnt[g] + dot(b2,Wl) + bl ; cnt via binary search on sorted batch ----
__global__ void out_kernel(const float* __restrict__ gsum, const int* __restrict__ batch,
                           const float* __restrict__ b2, const float* __restrict__ Wl,
                           const float* __restrict__ bl, float* __restrict__ out, int N) {
    int g = threadIdx.x;
    int lo = 0, hi = N;
    while (lo < hi) { int m = (lo + hi) >> 1; if (batch[m] < g) lo = m + 1; else hi = m; }
    int start = lo;
    hi = N;
    while (lo < hi) { int m = (lo + hi) >> 1; if (batch[m] < g + 1) lo = m + 1; else hi = m; }
    int cnt = lo - start;
    float c = 0.0f;
    for (int f = 0; f < 64; f++) c += b2[f] * Wl[f];
    out[g] = gsum[g] / fmaxf((float)cnt, 1.0f) + c + bl[0];
}

extern "C" void kernel_launch(void* const* d_in, const int* in_sizes, int n_in,
                              void* d_out, int out_size, void* d_ws, size_t ws_size,
                              hipStream_t stream) {
    const float* x  = (const float*)d_in[0];
    const int*   ei = (const int*)d_in[1];
    const int*   batch = (const int*)d_in[2];
    const float* W1 = (const float*)d_in[3];
    const float* b1 = (const float*)d_in[4];
    const float* W2 = (const float*)d_in[5];
    const float* b2 = (const float*)d_in[6];
    const float* Wl = (const float*)d_in[7];
    const float* bl = (const float*)d_in[8];
    float* out = (float*)d_out;

    const int N = N_NODES, E = N_EDGES;
    const int nblk = (N + 255) / 256;  // 391
    const int* src = ei;
    const int* dst = ei + E;

    // workspace layout (4B units; keep ebuf 8B-aligned)
    char* ws = (char*)d_ws;
    float*    dinv      = (float*)ws;     ws += 100096 * 4;
    int*      row_start = (int*)ws;       ws += 100112 * 4;   // N+1
    int*      cnt       = (int*)ws;       ws += 18944 * 4;    // NC*64
    int*      boff      = (int*)ws;       ws += 18944 * 4;
    int*      bucket_base = (int*)ws;     ws += 128 * 4;
    int*      csr       = (int*)ws;       ws += 1200128 * 4;
    int2*     ebuf      = (int2*)ws;      ws += 1200000 * 8;
    _Float16* buf1      = (_Float16*)ws;  ws += 6400000 * 2;  // t1 (fp16)
    ws += 128;
    float*    q         = (float*)ws;     ws += 100096 * 4;
    float*    w2l       = (float*)ws;     ws += 256 * 4;
    float*    gsum      = (float*)ws;     ws += 256 * 4;
    _Float16* whi       = (_Float16*)ws;  ws += 8192 * 2;
    _Float16* wlo       = (_Float16*)ws;  ws += 8192 * 2;

    hipMemsetAsync(gsum, 0, 256 * sizeof(float), stream);

    // CSR build: bucket count -> offsets -> bucket scatter -> per-bucket build (no global atomics)
    bkt_count<<<NC, 256, 0, stream>>>(dst, cnt, E);
    bkt_offsets<<<1, 1024, 0, stream>>>(cnt, boff, bucket_base, E);
    bkt_scatter<<<NC, 256, 0, stream>>>(src, dst, boff, ebuf, E);
    bkt_build<<<R_BUCKETS, 512, 0, stream>>>(ebuf, bucket_base, row_start, dinv, csr, N, E);

    w2l_kernel<<<1, 64, 0, stream>>>(W2, Wl, w2l);
    w1split_kernel<<<32, 256, 0, stream>>>(W1, whi, wlo);

    // Layer 1 GEMM on matrix cores: t1 = fp16(dinv*(x@W1))
    gemm_mfma<<<(N + 127) / 128, 256, 0, stream>>>(x, whi, wlo, dinv, buf1, N);

    // Layer-1 aggregation fused with folded layer-2 GEMM -> scalar q per node
    agg1_kernel<<<(N + AGG_NPB - 1) / AGG_NPB, 256, 0, stream>>>(
        buf1, row_start, csr, dinv, b1, w2l, q, N);

    // Layer-2 scalar aggregation + mean-pool numerator
    agg2_pool_kernel<<<nblk, 256, 0, stream>>>(q, row_start, csr, dinv, batch, gsum, N);

    out_kernel<<<1, 256, 0, stream>>>(gsum, batch, b2, Wl, bl, out, N);
}